// Round 9
// baseline (658.405 us; speedup 1.0000x reference)
//
#include <hip/hip_runtime.h>
#include <hip/hip_bf16.h>

// STMA block, MI355X. Round 14: dense motion MoE. k_motion_dense computes all
// 8 experts per token (weights L2-hot, 4x MFMA flops) and fuses combine +
// gelu + proj(64->256) + q-softmax in one kernel, eliminating the routing
// gather (alistM), the ycM 64MB round-trip, k_filld-M and k_mproj. Swapped-
// operand MFMA throughout (D[ch][tok] -> per-lane-uniform gate weight).
// hT double-buffered: 1 barrier/expert. qs aliases xmb (per-block safe).

typedef __hip_bfloat16 bf16;
typedef unsigned short u16;
typedef unsigned int   u32;
typedef __attribute__((ext_vector_type(8))) short short8;   // 8 bf16 = 4 VGPR
typedef __attribute__((ext_vector_type(4))) short s16x4;    // 4 bf16 = 2 VGPR
typedef __attribute__((ext_vector_type(4))) float f32x4;    // MFMA C/D

#define MFMA16(a,b,c) __builtin_amdgcn_mfma_f32_16x16x32_bf16(a,b,c,0,0,0)

__device__ __forceinline__ float b2f(bf16 v){ return __bfloat162float(v); }
__device__ __forceinline__ u16 f2bu(float f){
  union { __hip_bfloat16 hh; u16 us; } cv; cv.hh = __float2bfloat16(f); return cv.us;
}
__device__ __forceinline__ float bu2f(u16 v){ return __uint_as_float(((u32)v)<<16); }

// gelu via tanh-form sigmoid: x*sigmoid(1.5957691x + 0.0713548x^3).
__device__ __forceinline__ float geluf(float x){
  float t = x*x;
  float w = x * fmaf(-0.10294453f, t, -2.3022077f);
  float z = exp2f(w);
  return x * __builtin_amdgcn_rcpf(1.f + z);
}
__device__ __forceinline__ float siluf(float x){
  float z = exp2f(-1.442695f * x);
  return x * __builtin_amdgcn_rcpf(1.f + z);
}

__device__ __forceinline__ float wsum(float v){
#pragma unroll
  for (int o=32;o>0;o>>=1) v += __shfl_xor(v,o,64);
  return v;
}
__device__ __forceinline__ void top2(const float* lg, int& i1, int& i2, float& wA){
  i1 = 0; float v1 = lg[0];
#pragma unroll
  for (int e=1;e<8;e++) if (lg[e] > v1){ v1 = lg[e]; i1 = e; }
  i2 = 0; float v2 = -1e30f;
#pragma unroll
  for (int e=0;e<8;e++) if (e != i1 && lg[e] > v2){ v2 = lg[e]; i2 = e; }
  wA = 1.f/(1.f + expf(v2 - v1));
}

// packed 2-value wave reduction: even lanes sum(x), odd lanes sum(x*x).
__device__ __forceinline__ float sum2_wave(float x, int b0){
  float s = x, ss = x*x;
  float v = (b0 ? ss : s) + __shfl_xor(b0 ? s : ss, 1, 64);
  v += __shfl_xor(v, 2, 64);
  v += __shfl_xor(v, 4, 64);
  v += __shfl_xor(v, 8, 64);
  v += __shfl_xor(v, 16, 64);
  v += __shfl_xor(v, 32, 64);
  return v;
}

// 8-value reduce-scatter butterfly: lane l returns full-wave sum of p[l&7].
__device__ __forceinline__ float rsum8(const float p[8], int lane){
  int b0 = lane & 1, b1 = lane & 2, b2 = lane & 4;
  float w[4], u[2], v;
#pragma unroll
  for (int j=0;j<4;j++){
    float keep = b0 ? p[2*j+1] : p[2*j];
    float send = b0 ? p[2*j]   : p[2*j+1];
    w[j] = keep + __shfl_xor(send, 1, 64);
  }
#pragma unroll
  for (int i=0;i<2;i++){
    float keep = b1 ? w[2*i+1] : w[2*i];
    float send = b1 ? w[2*i]   : w[2*i+1];
    u[i] = keep + __shfl_xor(send, 2, 64);
  }
  {
    float keep = b2 ? u[1] : u[0];
    float send = b2 ? u[0] : u[1];
    v = keep + __shfl_xor(send, 4, 64);
  }
  v += __shfl_xor(v, 8, 64);
  v += __shfl_xor(v, 16, 64);
  v += __shfl_xor(v, 32, 64);
  return v;
}

// load short8 fragment from two 8B-aligned LDS halves
__device__ __forceinline__ short8 ld8(const u16* p){
  s16x4 lo = *(const s16x4*)p;
  s16x4 hi = *(const s16x4*)(p + 4);
  short8 r;
  r[0]=lo[0]; r[1]=lo[1]; r[2]=lo[2]; r[3]=lo[3];
  r[4]=hi[0]; r[5]=hi[1]; r[6]=hi[2]; r[7]=hi[3];
  return r;
}

// ---------------- init: zero cnts + body_w softmax ----------------
__global__ __launch_bounds__(64) void k_init(int* cnts, const float* __restrict__ body_w,
                                             float* __restrict__ bwv){
  int t = threadIdx.x;
  cnts[t] = 0;
  if (t < 8){
    float v[8]; float mx = -1e30f;
#pragma unroll
    for (int j=0;j<8;j++){ v[j] = body_w[t*8+j]; mx = fmaxf(mx, v[j]); }
    float s = 0.f;
#pragma unroll
    for (int j=0;j<8;j++){ v[j] = expf(v[j]-mx); s += v[j]; }
#pragma unroll
    for (int j=0;j<8;j++) bwv[t*8+j] = v[j]/s;
  }
}

// ---------------- merged repack: all 6 weight tensors, region-switched ----------------
__global__ __launch_bounds__(256) void k_repack_all(
    const float* __restrict__ s0, u16* __restrict__ d0,
    const float* __restrict__ s1, u16* __restrict__ d1,
    const float* __restrict__ s2, u16* __restrict__ d2,
    const float* __restrict__ s3, u16* __restrict__ d3,
    const float* __restrict__ s4, u16* __restrict__ d4,
    const float* __restrict__ s5, u16* __restrict__ d5){
  long g = (long)blockIdx.x*256 + threadIdx.x;
  if (g >= 4734976) return;
  const float* s; u16* d; int KC, N; long t;
  if      (g < 2097152){ s=s0; d=d0; KC=8;  N=1024; t=g; }
  else if (g < 4194304){ s=s1; d=d1; KC=32; N=256;  t=g-2097152; }
  else if (g < 4325376){ s=s2; d=d2; KC=2;  N=256;  t=g-4194304; }
  else if (g < 4456448){ s=s3; d=d3; KC=8;  N=64;   t=g-4325376; }
  else if (g < 4472832){ s=s4; d=d4; KC=2;  N=256;  t=g-4456448; }
  else                 { s=s5; d=d5; KC=16; N=512;  t=g-4472832; }
  int NT = N >> 4;
  int j = t & 7, n = (t>>3) & 15, q = (t>>7) & 3;
  long r2 = t >> 9;
  int kc = (int)(r2 % KC); long r3 = r2 / KC;
  int nt = (int)(r3 % NT); int e = (int)(r3 / NT);
  int k = kc*32 + q*8 + j;
  d[t] = f2bu(s[((size_t)(e*(KC*32) + k))*N + nt*16 + n]);
}

// ---------------- direct fill (text only): block-aggregated atomics ----------------
__global__ __launch_bounds__(256) void k_filld(const int2* __restrict__ eidx, int n, int stride,
                                               int* __restrict__ cnt, int* __restrict__ alist){
  __shared__ int lc[8], gb[8], lc2[8];
  int tid = threadIdx.x;
  if (tid < 8){ lc[tid] = 0; lc2[tid] = 0; }
  __syncthreads();
  for (int i = blockIdx.x*256 + tid; i < n; i += gridDim.x*256){
    int2 e = eidx[i];
    atomicAdd(&lc[e.x], 1); atomicAdd(&lc[e.y], 1);
  }
  __syncthreads();
  if (tid < 8) gb[tid] = atomicAdd(&cnt[tid], lc[tid]);
  __syncthreads();
  for (int i = blockIdx.x*256 + tid; i < n; i += gridDim.x*256){
    int2 e = eidx[i];
    int s0 = atomicAdd(&lc2[e.x], 1); alist[e.x*stride + gb[e.x] + s0] = i*2;
    int s1 = atomicAdd(&lc2[e.y], 1); alist[e.y*stride + gb[e.y] + s1] = i*2 + 1;
  }
}

// ---------------- pre: LN + pos + gate ----------------
__global__ __launch_bounds__(256) void k_text_pre(
    const float* __restrict__ xf, const float* __restrict__ tg, const float* __restrict__ tb,
    const float* __restrict__ tpos, const float* __restrict__ gw,
    u16* __restrict__ xtb, int2* __restrict__ eidxT, float2* __restrict__ ewT){
  int tok = blockIdx.x, tid = threadIdx.x;
  int n = tok % 77;
  __shared__ float redw[32], lgs[8];
  int w = tid >> 6, ln = tid & 63;
  int b0 = tid & 1;
  float xv = xf[tok*256 + tid];
  float v = sum2_wave(xv, b0);
  if (ln < 2) redw[w*2 + ln] = v;
  __syncthreads();
  float mean = (redw[0]+redw[2]+redw[4]+redw[6]) * (1.f/256.f);
  float var  = (redw[1]+redw[3]+redw[5]+redw[7]) * (1.f/256.f) - mean*mean;
  float r = rsqrtf(var + 1e-5f);
  float xn = (xv - mean)*r*tg[tid] + tb[tid] + tpos[n*256 + tid];
  xtb[tok*256 + tid] = f2bu(xn);
  float p[8];
#pragma unroll
  for (int e=0;e<8;e++) p[e] = xn * gw[tid*8 + e];
  float vv = rsum8(p, ln);
  __syncthreads();
  if (ln < 8) redw[w*8 + ln] = vv;
  __syncthreads();
  if (tid < 8) lgs[tid] = redw[tid] + redw[8+tid] + redw[16+tid] + redw[24+tid];
  __syncthreads();
  if (tid == 0){
    int i1, i2; float wA; top2(lgs, i1, i2, wA);
    eidxT[tok] = make_int2(i1, i2);
    ewT[tok] = make_float2(wA, 1.f - wA);
  }
}

// motion pre: LN + pos + gate -> dense float8 gate weights (0 except top2)
__global__ __launch_bounds__(256) void k_motion_pre(
    const float* __restrict__ x, const float* __restrict__ ng, const float* __restrict__ nb,
    const float* __restrict__ mpos, const float* __restrict__ gw,
    u16* __restrict__ xmb, float* __restrict__ w8){
  int tok = blockIdx.x*4 + (threadIdx.x >> 6);
  int d = threadIdx.x & 63;
  int b0 = d & 1;
  float xv = x[(size_t)tok*64 + d];
  float v = sum2_wave(xv, b0);
  float o = __shfl_xor(v, 1, 64);
  float sf  = b0 ? o : v;
  float ssf = b0 ? v : o;
  float mean = sf * (1.f/64.f);
  float var  = ssf * (1.f/64.f) - mean*mean;
  float r = rsqrtf(var + 1e-5f);
  int h = tok & 7; int t = (tok >> 3) & 255;
  float xn = (xv - mean)*r*ng[d] + nb[d] + mpos[(t*8+h)*64 + d];
  xmb[(size_t)tok*64 + d] = f2bu(xn);
  float p[8];
#pragma unroll
  for (int e=0;e<8;e++) p[e] = xn * gw[d*8 + e];
  float vv = rsum8(p, d);
  float lg[8];
#pragma unroll
  for (int e=0;e<8;e++) lg[e] = __shfl(vv, e, 64);
  if (d < 8){
    int i1, i2; float wA; top2(lg, i1, i2, wA);
    float wv = (d == i1) ? wA : ((d == i2) ? (1.f - wA) : 0.f);
    w8[(size_t)tok*8 + d] = wv;
  }
}

// ---------------- dense motion MoE + combine + gelu + proj + q-softmax ----------------
// 32 tokens/block, 4 waves (mt = token half, wp = channel half). All 8 experts
// computed; combine weight uniform per lane (D[ch][tok]). hT double-buffered:
// 1 barrier/expert. qs may alias xmb (block writes only rows it consumed).
__global__ __launch_bounds__(256, 4) void k_motion_dense(
    const u16* __restrict__ xmb, const float* __restrict__ w8,
    const u16* __restrict__ w1pk, const float* __restrict__ fc1b,
    const u16* __restrict__ w2pk, const float* __restrict__ fc2b,
    const u16* __restrict__ wppk, const float* __restrict__ pb,
    u16* __restrict__ mf, u16* __restrict__ qs){
  int t0 = blockIdx.x*32, tid = threadIdx.x;
  __shared__ u16 hT[2][32*264];     // 33.8 KB, [tok][256ch] dbuf
  __shared__ u16 xs[32*72];         // x stage; reused as ys (gelu(y))
  __shared__ float ws[256];         // [32 tok][8 e]
  { int row = tid >> 3, c0 = (tid & 7)*8;
    *(short8*)&xs[row*72 + c0] = *(const short8*)(xmb + (size_t)(t0+row)*64 + c0); }
  ws[tid] = w8[(size_t)t0*8 + tid];
  __syncthreads();
  int lane = tid & 63, w = tid >> 6;
  int n = lane & 15, q = lane >> 4;
  int mt = w & 1, wp = w >> 1;
  int tok = mt*16 + n;
  short8 x0 = *(const short8*)&xs[tok*72 + q*8];
  short8 x1 = *(const short8*)&xs[tok*72 + 32 + q*8];
  float yacc[2][4];
#pragma unroll
  for (int i=0;i<2;i++)
#pragma unroll
    for (int r=0;r<4;r++) yacc[i][r] = 0.f;
#pragma unroll 1
  for (int e=0;e<8;e++){
    u16* hb = hT[e & 1];
    const short8* b1 = (const short8*)(w1pk + (size_t)e*16384);
    // fc1: wave covers nt = wp*8..wp*8+7
#pragma unroll
    for (int i=0;i<8;i++){
      int nt = wp*8 + i;
      f32x4 acc = {0.f,0.f,0.f,0.f};
      acc = MFMA16(b1[(nt*2+0)*64 + lane], x0, acc);
      acc = MFMA16(b1[(nt*2+1)*64 + lane], x1, acc);
      f32x4 bias = *(const f32x4*)(fc1b + e*256 + nt*16 + q*4);
      s16x4 o;
#pragma unroll
      for (int r=0;r<4;r++) o[r] = (short)f2bu(geluf(acc[r] + bias[r]));
      *(s16x4*)&hb[tok*264 + nt*16 + q*4] = o;
    }
    __syncthreads();                       // hb writes visible; prev buf free
    short8 a2[8];
#pragma unroll
    for (int kc=0;kc<8;kc++) a2[kc] = ld8(&hb[tok*264 + kc*32 + q*8]);
    const short8* b2 = (const short8*)(w2pk + (size_t)e*16384);
    float we = ws[tok*8 + e];
#pragma unroll
    for (int i=0;i<2;i++){
      int nt = wp*2 + i;
      f32x4 acc = {0.f,0.f,0.f,0.f};
#pragma unroll
      for (int kc=0;kc<8;kc++) acc = MFMA16(b2[(nt*8+kc)*64 + lane], a2[kc], acc);
      f32x4 bias = *(const f32x4*)(fc2b + e*64 + nt*16 + q*4);
#pragma unroll
      for (int r=0;r<4;r++) yacc[i][r] += we * (acc[r] + bias[r]);
    }
  }
  // gelu(y) -> ys (= xs space; x frags long since in registers)
#pragma unroll
  for (int i=0;i<2;i++){
    int ch0 = (wp*2 + i)*16 + q*4;
    s16x4 o;
#pragma unroll
    for (int r=0;r<4;r++) o[r] = (short)f2bu(geluf(yacc[i][r]));
    *(s16x4*)&xs[tok*72 + ch0] = o;
  }
  __syncthreads();
  short8 bx0 = *(const short8*)&xs[tok*72 + q*8];
  short8 bx1 = *(const short8*)&xs[tok*72 + 32 + q*8];
  const short8* bp = (const short8*)wppk;
  float vals[4][4];                 // query channels, wp==1 waves only
#pragma unroll
  for (int i8=0;i8<8;i8++){
    int i = wp*8 + i8;
    f32x4 acc = {0.f,0.f,0.f,0.f};
    acc = MFMA16(bp[(i*2+0)*64 + lane], bx0, acc);
    acc = MFMA16(bp[(i*2+1)*64 + lane], bx1, acc);
    f32x4 bias = *(const f32x4*)(pb + i*16 + q*4);
    s16x4 o;
#pragma unroll
    for (int r=0;r<4;r++){
      float v = acc[r] + bias[r];
      if (wp == 1 && i8 >= 4) vals[i8-4][r] = v;
      o[r] = (short)f2bu(v);
    }
    *(s16x4*)(mf + (size_t)(t0+tok)*256 + i*16 + q*4) = o;
  }
  if (wp == 1){
    // softmax over token's 64 query channels: local 16 + reduce over q lanes
    float m = -1e30f;
#pragma unroll
    for (int j=0;j<4;j++)
#pragma unroll
      for (int r=0;r<4;r++) m = fmaxf(m, vals[j][r]);
    m = fmaxf(m, __shfl_xor(m, 16, 64));
    m = fmaxf(m, __shfl_xor(m, 32, 64));
    float ev[4][4]; float s = 0.f;
#pragma unroll
    for (int j=0;j<4;j++)
#pragma unroll
      for (int r=0;r<4;r++){ ev[j][r] = expf(vals[j][r] - m); s += ev[j][r]; }
    s += __shfl_xor(s, 16, 64);
    s += __shfl_xor(s, 32, 64);
    float inv = __builtin_amdgcn_rcpf(s);
#pragma unroll
    for (int j=0;j<4;j++){
      s16x4 o;
#pragma unroll
      for (int r=0;r<4;r++) o[r] = (short)f2bu(ev[j][r]*inv);
      *(s16x4*)(qs + (size_t)(t0+tok)*64 + j*16 + q*4) = o;
    }
  }
}

// ---------------- text MoE (MFMA): 16-token tiles ----------------
__global__ __launch_bounds__(256) void k_text_moe(
    const u16* __restrict__ xtb, const int* __restrict__ alistT, const int* __restrict__ cnts,
    const u16* __restrict__ w1pk, const float* __restrict__ fc1b,
    const u16* __restrict__ w2pk, const float* __restrict__ fc2b,
    float* __restrict__ ycT){
  int e = blockIdx.y, tile = blockIdx.x, tid = threadIdx.x;
  int cnt = cnts[e]; int base = tile*16;
  if (base >= cnt) return;
  int nn = min(16, cnt - base); int off = e*4928;
  __shared__ int toks[16];
  __shared__ u16 xs[16*280];
  __shared__ u16 hT[16*1048];
  if (tid < 16) toks[tid] = alistT[off + base + min(tid, nn-1)];
  __syncthreads();
  { int row = tid >> 4, c0 = (tid & 15)*16;
    const short8* sp = (const short8*)(xtb + (size_t)(toks[row]>>1)*256 + c0);
    short8 v0 = sp[0], v1 = sp[1];
    *(short8*)&xs[row*280 + c0] = v0;
    *(short8*)&xs[row*280 + c0 + 8] = v1; }
  __syncthreads();
  int lane = tid & 63, w = tid >> 6;
  int n = lane & 15, q = lane >> 4;
  short8 a_[8];
#pragma unroll
  for (int kc=0;kc<8;kc++) a_[kc] = *(const short8*)&xs[n*280 + kc*32 + q*8];
  const short8* b1 = (const short8*)(w1pk + (size_t)e*262144);
#pragma unroll 1
  for (int i=0;i<16;i++){
    int nt = w*16 + i;
    f32x4 acc = {0.f,0.f,0.f,0.f};
#pragma unroll
    for (int kc=0;kc<8;kc++) acc = MFMA16(a_[kc], b1[(nt*8+kc)*64 + lane], acc);
    float bias = fc1b[e*1024 + nt*16 + n];
#pragma unroll
    for (int r=0;r<4;r++)
      hT[(q*4 + r)*1048 + nt*16 + n] = f2bu(geluf(acc[r] + bias));
  }
  __syncthreads();
  const short8* b2 = (const short8*)(w2pk + (size_t)e*262144);
  f32x4 acc[4];
#pragma unroll
  for (int i=0;i<4;i++) acc[i] = (f32x4){0.f,0.f,0.f,0.f};
#pragma unroll 1
  for (int kc=0;kc<32;kc++){
    short8 a = *(const short8*)&hT[n*1048 + kc*32 + q*8];
#pragma unroll
    for (int i=0;i<4;i++){
      int nt = w*4 + i;
      acc[i] = MFMA16(a, b2[(nt*32+kc)*64 + lane], acc[i]);
    }
  }
#pragma unroll
  for (int i=0;i<4;i++){
    int nt = w*4 + i;
    float bias = fc2b[e*256 + nt*16 + n];
#pragma unroll
    for (int r=0;r<4;r++){
      int row = q*4 + r;
      if (row < nn) ycT[(size_t)toks[row]*256 + nt*16 + n] = acc[i][r] + bias;
    }
  }
}

// combine 2 expert contributions (gate-weighted), gelu, proj 256->128 -> tfeat
__global__ __launch_bounds__(128) void k_text_combine(
    const float* __restrict__ ycT, const float2* __restrict__ ewT,
    const float* __restrict__ pw, const float* __restrict__ pb,
    float* __restrict__ tfeat){
  int t = blockIdx.x, tid = threadIdx.x;
  __shared__ float gy[256];
  float2 w = ewT[t];
  for (int c=tid; c<256; c+=128){
    float y = w.x*ycT[(size_t)(t*2)*256 + c] + w.y*ycT[(size_t)(t*2+1)*256 + c];
    gy[c] = geluf(y);
  }
  __syncthreads();
  float a = pb[tid];
  for (int k=0;k<256;k++) a += gy[k] * pw[k*128 + tid];
  tfeat[(size_t)t*128 + tid] = a;
}

// ---------------- eo = silu(emb) @ (2048x1024) + b : split-K tiled f32 ----------------
__global__ __launch_bounds__(256) void k_eo1(const float* __restrict__ emb, const float* __restrict__ ew,
                      float* __restrict__ ep){
  int ct = blockIdx.x & 15;
  int ks = blockIdx.x >> 4;
  int tid = threadIdx.x;
  int k0 = ks*128, c0 = ct*64;
  __shared__ float aS[128*68];
  __shared__ float bS[128*64];
#pragma unroll
  for (int i=0;i<8;i++){
    int idx4 = tid + i*256;
    int b = idx4 >> 5, kq = idx4 & 31;
    f32x4 v = *(const f32x4*)(emb + (size_t)b*2048 + k0 + kq*4);
    aS[(kq*4+0)*68 + b] = siluf(v[0]);
    aS[(kq*4+1)*68 + b] = siluf(v[1]);
    aS[(kq*4+2)*68 + b] = siluf(v[2]);
    aS[(kq*4+3)*68 + b] = siluf(v[3]);
  }
#pragma unroll
  for (int i=0;i<8;i++){
    int idx4 = tid + i*256;
    int kk = idx4 >> 4, cq = idx4 & 15;
    *(f32x4*)&bS[kk*64 + cq*4] = *(const f32x4*)(ew + (size_t)(k0+kk)*1024 + c0 + cq*4);
  }
  __syncthreads();
  int cg = tid & 15, bg = tid >> 4;
  f32x4 acc[4] = {{0.f,0.f,0.f,0.f},{0.f,0.f,0.f,0.f},{0.f,0.f,0.f,0.f},{0.f,0.f,0.f,0.f}};
#pragma unroll 4
  for (int kk=0;kk<128;kk++){
    f32x4 a = *(const f32x4*)&aS[kk*68 + bg*4];
    f32x4 bb = *(const f32x4*)&bS[kk*64 + cg*4];
#pragma unroll
    for (int i=0;i<4;i++){
      acc[i][0] += a[i]*bb[0];
      acc[i][1] += a[i]*bb[1];
      acc[i][2] += a[i]*bb[2];
      acc[i][3] += a[i]*bb[3];
    }
  }
#pragma unroll
  for (int i=0;i<4;i++){
    int b = bg*4 + i;
    *(f32x4*)&ep[((size_t)(ks*64 + b))*1024 + c0 + cg*4] = acc[i];
  }
}

__global__ __launch_bounds__(256) void k_eo2(const float* __restrict__ ep, const float* __restrict__ ebias,
                      float* __restrict__ eo){
  int idx = blockIdx.x*256 + threadIdx.x;
  int c = idx & 1023;
  float s = ebias[c];
#pragma unroll
  for (int ks=0;ks<16;ks++) s += ep[(size_t)ks*65536 + idx];
  eo[idx] = s;
}

// ---------------- attention: single-pass LDS-resident, MFMA PV ----------------
#define AT_STRIDE 364
__global__ __launch_bounds__(512) void k_attn(const float* __restrict__ tfeat, const u16* __restrict__ mf,
                       const float* __restrict__ src_mask, const int* __restrict__ cond,
                       u16* __restrict__ attnT){
  int b = blockIdx.x >> 3; int h = blockIdx.x & 7;
  int tid = threadIdx.x; int c = tid & 63; int part = tid >> 6;
  __shared__ u16 ebT[64*AT_STRIDE];
  __shared__ u16 vbT[64*AT_STRIDE];
  __shared__ float colmax[64], colsum[64], red[512];
  float tc = ((cond[b] % 10) > 0) ? 1.f : 0.f;
  float negt = (1.f - tc) * (-1e6f);

  float mx = -1e30f;
  for (int k = 0; k < 11; k++){
    int n0 = part*44 + k*4;
    s16x4 kb4, vb4;
#pragma unroll
    for (int jj = 0; jj < 4; jj++){
      int n = n0 + jj;
      float kv, vv;
      if (n < 77){
        const float* trow = tfeat + (b*77+n)*128;
        kv = trow[c] + negt;
        vv = trow[64 + c] * tc;
      } else if (n < 333){
        int t = n - 77; float smv = src_mask[b*256 + t];
        const u16* mrow = mf + ((size_t)(b*256+t)*8+h)*256;
        kv = bu2f(mrow[64 + c]) + (1.f - smv)*(-1e6f);
        vv = bu2f(mrow[128 + c]) * smv;
      } else { kv = -1e30f; vv = 0.f; }
      kb4[jj] = (short)f2bu(kv);
      vb4[jj] = (short)f2bu(vv);
      mx = fmaxf(mx, kv);
    }
    *(s16x4*)&ebT[c*AT_STRIDE + n0] = kb4;
    *(s16x4*)&vbT[c*AT_STRIDE + n0] = vb4;
  }
  red[tid] = mx; __syncthreads();
  if (part == 0){
    float m = red[c];
#pragma unroll
    for (int p=1;p<8;p++) m = fmaxf(m, red[p*64 + c]);
    colmax[c] = m;
  }
  __syncthreads();
  { int rowc = tid >> 3, j = tid & 7;
    float cm = colmax[rowc];
    float s = 0.f;
    for (int k = 0; k < 11; k++){
      int n0 = (j*11 + k)*4;
      s16x4 v4 = *(const s16x4*)&ebT[rowc*AT_STRIDE + n0];
      float e0 = expf(bu2f((u16)v4[0]) - cm);
      float e1 = expf(bu2f((u16)v4[1]) - cm);
      float e2 = expf(bu2f((u16)v4[2]) - cm);
      float e3 = expf(bu2f((u16)v4[3]) - cm);
      s += (e0+e1) + (e2+e3);
      s16x4 o;
      o[0]=(short)f2bu(e0); o[1]=(short)f2bu(e1); o[2]=(short)f2bu(e2); o[3]=(short)f2bu(e3);
      *(s16x4*)&ebT[rowc*AT_STRIDE + n0] = o;
    }
    red[tid] = s;
  }
  __syncthreads();
  if (tid < 64){
    float t2 = 0.f;
#pragma unroll
    for (int p=0;p<8;p++) t2 += red[tid*8 + p];
    colsum[tid] = t2;
  }
  __syncthreads();
  int lane = tid & 63, w = tid >> 6;
  int n16 = lane & 15, q = lane >> 4;
  int mt = w >> 1;
  int ntb = (w & 1) * 2;
  f32x4 acc0 = {0.f,0.f,0.f,0.f}, acc1 = {0.f,0.f,0.f,0.f};
  const u16* ea = &ebT[(mt*16 + n16)*AT_STRIDE + q*8];
  const u16* v0p = &vbT[(ntb*16 + n16)*AT_STRIDE + q*8];
  const u16* v1p = &vbT[((ntb+1)*16 + n16)*AT_STRIDE + q*8];
#pragma unroll
  for (int kc = 0; kc < 11; kc++){
    short8 a  = ld8(ea  + kc*32);
    short8 b0 = ld8(v0p + kc*32);
    short8 b1 = ld8(v1p + kc*32);
    acc0 = MFMA16(a, b0, acc0);
    acc1 = MFMA16(a, b1, acc1);
  }
  float inv[4];
#pragma unroll
  for (int r=0;r<4;r++) inv[r] = __builtin_amdgcn_rcpf(colsum[mt*16 + q*4 + r]);
  u16* outp = attnT + (size_t)(b*8+h)*4096;
  int d0 = mt*16 + q*4;
  {
    int l = ntb*16 + n16;
    s16x4 o;
#pragma unroll
    for (int r=0;r<4;r++) o[r] = (short)f2bu(acc0[r]*inv[r]);
    *(s16x4*)(outp + l*64 + d0) = o;
  }
  {
    int l = (ntb+1)*16 + n16;
    s16x4 o;
#pragma unroll
    for (int r=0;r<4;r++) o[r] = (short)f2bu(acc1[r]*inv[r]);
    *(s16x4*)(outp + l*64 + d0) = o;
  }
}

// ---------------- y_t = qs @ attn per (b,h): M=256,K=64,N=64 MFMA ----------------
__global__ __launch_bounds__(256) void k_yt(const u16* __restrict__ qs, const u16* __restrict__ attnT,
                                            u16* __restrict__ yt){
  int b = blockIdx.x >> 3; int h = blockIdx.x & 7;
  int tid = threadIdx.x;
  int lane = tid & 63, w = tid >> 6;
  int n = lane & 15, q = lane >> 4;
  const u16* qsb = qs + ((size_t)(b*256)*8 + h)*64;
  const u16* ab  = attnT + (size_t)(b*8+h)*4096;
  f32x4 acc[4][4];
#pragma unroll
  for (int mt=0;mt<4;mt++)
#pragma unroll
    for (int nt=0;nt<4;nt++) acc[mt][nt] = (f32x4){0.f,0.f,0.f,0.f};
#pragma unroll
  for (int kc=0;kc<2;kc++){
    short8 a_[4], b_[4];
#pragma unroll
    for (int mt=0;mt<4;mt++){
      int t = w*64 + mt*16 + n;
      a_[mt] = *(const short8*)(qsb + (size_t)t*512 + kc*32 + q*8);
    }
#pragma unroll
    for (int nt=0;nt<4;nt++){
      int l = nt*16 + n;
      b_[nt] = *(const short8*)(ab + l*64 + kc*32 + q*8);
    }
#pragma unroll
    for (int mt=0;mt<4;mt++)
#pragma unroll
      for (int nt=0;nt<4;nt++)
        acc[mt][nt] = MFMA16(a_[mt], b_[nt], acc[mt][nt]);
  }
#pragma unroll
  for (int mt=0;mt<4;mt++)
#pragma unroll
    for (int nt=0;nt<4;nt++){
      int l = nt*16 + n;
#pragma unroll
      for (int r=0;r<4;r++){
        int t = w*64 + mt*16 + q*4 + r;
        yt[((size_t)(b*256+t)*8 + h)*64 + l] = f2bu(acc[mt][nt][r]);
      }
    }
}

// ---------------- j2: body mix + y_t, LN(512), modulate, silu -> sbuf ----------------
__global__ __launch_bounds__(256) void k_j2(const u16* __restrict__ mf, const u16* __restrict__ yt,
                     const float* __restrict__ bwv, const float* __restrict__ eo,
                     const float* __restrict__ sb_ng, const float* __restrict__ sb_nb,
                     float* __restrict__ sbuf){
  int blk = blockIdx.x; int b = blk >> 8; int t = blk & 255;
  int tid = threadIdx.x;
  __shared__ float mfl[512], red[4];
#pragma unroll
  for (int ii=0; ii<2; ii++){
    int idx = tid + ii*256; int h = idx >> 6; int dd = idx & 63;
    mfl[idx] = bu2f(mf[((size_t)(b*256+t)*8+h)*256 + dd]);
  }
  __syncthreads();
  int w = tid >> 6, ln = tid & 63;
  float out[2];
#pragma unroll
  for (int ii=0; ii<2; ii++){
    int idx = tid + ii*256; int h = idx >> 6; int l = idx & 63;
    float a = bu2f(yt[((size_t)(b*256+t)*8 + h)*64 + l]);
    float bs = 0.f;
#pragma unroll
    for (int lh=0; lh<8; lh++) bs += bwv[h*8 + lh] * mfl[lh*64 + l];
    out[ii] = a + bs;
  }
  float psum = wsum(out[0] + out[1]);
  if (ln == 0) red[w] = psum;
  __syncthreads();
  float mean = (red[0]+red[1]+red[2]+red[3]) * (1.f/512.f);
  __syncthreads();
  float c0 = out[0]-mean, c1 = out[1]-mean;
  float pv = wsum(c0*c0 + c1*c1);
  if (ln == 0) red[w] = pv;
  __syncthreads();
  float var = (red[0]+red[1]+red[2]+red[3]) * (1.f/512.f);
  float r = rsqrtf(var + 1e-5f);
#pragma unroll
  for (int ii=0; ii<2; ii++){
    int c = tid + ii*256;
    float hn = (out[ii]-mean)*r*sb_ng[c] + sb_nb[c];
    float e1 = eo[b*1024 + c], e2 = eo[b*1024 + 512 + c];
    float hm = hn*(1.f + e1) + e2;
    sbuf[(size_t)blk*512 + c] = siluf(hm);
  }
}

// ---------------- out = x + sbuf @ W + b (MFMA, 32-row tiles, in-place d_out) ----------------
__global__ __launch_bounds__(256) void k_out(const u16* __restrict__ wpk,
                      const float* __restrict__ bias, const float* __restrict__ x,
                      float* __restrict__ out){
  int r0 = blockIdx.x*32, tid = threadIdx.x;
  __shared__ u16 xs[32*536];
  { int row = tid >> 3, c0 = (tid & 7)*64;
    const f32x4* sp = (const f32x4*)(out + (size_t)(r0+row)*512 + c0);
#pragma unroll
    for (int j=0;j<8;j++){
      f32x4 va = sp[2*j], vb = sp[2*j+1];
      short8 o;
      o[0]=(short)f2bu(va[0]); o[1]=(short)f2bu(va[1]); o[2]=(short)f2bu(va[2]); o[3]=(short)f2bu(va[3]);
      o[4]=(short)f2bu(vb[0]); o[5]=(short)f2bu(vb[1]); o[6]=(short)f2bu(vb[2]); o[7]=(short)f2bu(vb[3]);
      *(short8*)&xs[row*536 + c0 + 8*j] = o;
    } }
  __syncthreads();
  int lane = tid & 63, w = tid >> 6;
  int n = lane & 15, q = lane >> 4;
  int mt = w & 1;
  short8 a_[16];
#pragma unroll
  for (int kc=0;kc<16;kc++) a_[kc] = *(const short8*)&xs[(mt*16 + n)*536 + kc*32 + q*8];
  const short8* bp = (const short8*)wpk;
#pragma unroll 1
  for (int i=0;i<16;i++){
    int nt = (w>>1)*16 + i;
    f32x4 acc = {0.f,0.f,0.f,0.f};
#pragma unroll
    for (int kc=0;kc<16;kc++) acc = MFMA16(a_[kc], bp[(nt*16+kc)*64 + lane], acc);
    int col = nt*16 + n;
    float bv = bias[col];
#pragma unroll
    for (int r=0;r<4;r++){
      size_t rowg = (size_t)(r0 + mt*16 + q*4 + r);
      out[rowg*512 + col] = acc[r] + bv + x[rowg*512 + col];
    }
  }
}

extern "C" void kernel_launch(void* const* d_in, const int* in_sizes, int n_in,
                              void* d_out, int out_size, void* d_ws, size_t ws_size,
                              hipStream_t stream) {
  (void)in_sizes; (void)n_in; (void)out_size; (void)ws_size;
  const float* x        = (const float*)d_in[0];
  const float* xf       = (const float*)d_in[1];
  const float* emb      = (const float*)d_in[2];
  const float* src_mask = (const float*)d_in[3];
  const float* norm_g   = (const float*)d_in[4];
  const float* norm_b   = (const float*)d_in[5];
  const float* tnorm_g  = (const float*)d_in[6];
  const float* tnorm_b  = (const float*)d_in[7];
  const float* m_pos    = (const float*)d_in[8];
  const float* m_gate   = (const float*)d_in[9];
  const float* m_fc1w   = (const float*)d_in[10];
  const float* m_fc1b   = (const float*)d_in[11];
  const float* m_fc2w   = (const float*)d_in[12];
  const float* m_fc2b   = (const float*)d_in[13];
  const float* m_projw  = (const float*)d_in[14];
  const float* m_projb  = (const float*)d_in[15];
  const float* t_pos    = (const float*)d_in[16];
  const float* t_gate   = (const float*)d_in[17];
  const float* t_fc1w   = (const float*)d_in[18];
  const float* t_fc1b   = (const float*)d_in[19];
  const float* t_fc2w   = (const float*)d_in[20];
  const float* t_fc2b   = (const float*)d_in[21];
  const float* t_projw  = (const float*)d_in[22];
  const float* t_projb  = (const float*)d_in[23];
  const float* body_w   = (const float*)d_in[24];
  const float* sb_embw  = (const float*)d_in[25];
  const float* sb_embb  = (const float*)d_in[26];
  const float* sb_ng    = (const float*)d_in[27];
  const float* sb_nb    = (const float*)d_in[28];
  const float* sb_outw  = (const float*)d_in[29];
  const float* sb_outb  = (const float*)d_in[30];
  const int*   cond     = (const int*)d_in[31];

  // ---- workspace, manual lifetime aliasing ----
  char* base = (char*)d_ws;
  size_t o = 0;
  auto alloc = [&](size_t bytes)->char*{ char* r = base + o; o += (bytes + 255) & ~(size_t)255; return r; };
  u16*  mf      = (u16*)alloc(67108864);    // motion_feat bf16, live to end
  char* R       = alloc(33554432);          // aliased region
  float* ep     = (float*)(R);              // eo partials, dead before xtb use
  u16*  xtb     = (u16*)(R);                // dead after k_text_moe
  float* ycT    = (float*)(R + 4194304);    // dead after k_text_combine
  u16*  attnT   = (u16*)(R);                // written after xtb/ycT dead
  u16*  yt      = (u16*)(R + 8388608);
  u16*  xmb     = (u16*)alloc(16777216);    // x staged; qs aliases (per-block safe)
  u16*  qs      = xmb;
  u16*  t1pk    = (u16*)alloc(4194304);
  u16*  t2pk    = (u16*)alloc(4194304);
  u16*  m1pk    = (u16*)alloc(262144);
  u16*  m2pk    = (u16*)alloc(262144);
  u16*  mppk    = (u16*)alloc(32768);
  u16*  wopk    = (u16*)alloc(524288);
  int2* eidxT   = (int2*)alloc(39424);
  float2* ewT   = (float2*)alloc(39424);
  float* w8     = (float*)alloc(4194304);   // [131072][8] dense gate weights
  int*  alistT  = (int*)alloc(157696);      // [8][4928] strided
  int*  cnts    = (int*)alloc(256);
  float* tfeat  = (float*)alloc(2523136);
  float* eo     = (float*)alloc(262144);
  float* bwv    = (float*)alloc(256);
  float* sbuf   = (float*)d_out;

  // setup (merged): init + one repack + eo GEMM
  k_init<<<1, 64, 0, stream>>>(cnts, body_w, bwv);
  k_repack_all<<<18496, 256, 0, stream>>>(t_fc1w, t1pk, t_fc2w, t2pk, m_fc1w, m1pk,
                                          m_fc2w, m2pk, m_projw, mppk, sb_outw, wopk);
  k_eo1<<<256, 256, 0, stream>>>(emb, sb_embw, ep);
  k_eo2<<<256, 256, 0, stream>>>(ep, sb_embb, eo);

  // pre + text routing (motion path needs no routing)
  k_text_pre<<<4928, 256, 0, stream>>>(xf, tnorm_g, tnorm_b, t_pos, t_gate, xtb, eidxT, ewT);
  k_motion_pre<<<32768, 256, 0, stream>>>(x, norm_g, norm_b, m_pos, m_gate, xmb, w8);
  k_filld<<<32, 256, 0, stream>>>(eidxT, 4928, 4928, cnts, alistT);

  // text MoE (MFMA) then combine
  k_text_moe<<<dim3(308, 8), 256, 0, stream>>>(xtb, alistT, cnts, t1pk, t_fc1b, t2pk, t_fc2b, ycT);
  k_text_combine<<<4928, 128, 0, stream>>>(ycT, ewT, t_projw, t_projb, tfeat);

  // dense motion MoE + combine + proj + q-softmax, one kernel
  k_motion_dense<<<4096, 256, 0, stream>>>(xmb, w8, m1pk, m_fc1b, m2pk, m_fc2b,
                                           mppk, m_projb, mf, qs);

  // attention + epilogue
  k_attn<<<512, 512, 0, stream>>>(tfeat, mf, src_mask, cond, attnT);
  k_yt<<<512, 256, 0, stream>>>(qs, attnT, yt);
  k_j2<<<16384, 256, 0, stream>>>(mf, yt, bwv, eo, sb_ng, sb_nb, sbuf);
  k_out<<<512, 256, 0, stream>>>(wopk, sb_outb, x, (float*)d_out);
}

// Round 10
// 475.541 us; speedup vs baseline: 1.3845x; 1.3845x over previous
//
#include <hip/hip_runtime.h>
#include <hip/hip_bf16.h>

// STMA block, MI355X. Round 15: revert to round-13 kernel (best: 478.9 us).
// Round-14's dense motion MoE was 5x slower (305 us, MfmaUtil 10%, 9.5M bank
// conflicts, 16 barriers/block) - routing was NOT the bottleneck. The ~61us
// k_motion_moe cost is structure-invariant (3 implementations within 2%).

typedef __hip_bfloat16 bf16;
typedef unsigned short u16;
typedef unsigned int   u32;
typedef __attribute__((ext_vector_type(8))) short short8;   // 8 bf16 = 4 VGPR
typedef __attribute__((ext_vector_type(4))) short s16x4;    // 4 bf16 = 2 VGPR
typedef __attribute__((ext_vector_type(4))) float f32x4;    // MFMA C/D

#define MFMA16(a,b,c) __builtin_amdgcn_mfma_f32_16x16x32_bf16(a,b,c,0,0,0)

__device__ __forceinline__ float b2f(bf16 v){ return __bfloat162float(v); }
__device__ __forceinline__ u16 f2bu(float f){
  union { __hip_bfloat16 hh; u16 us; } cv; cv.hh = __float2bfloat16(f); return cv.us;
}
__device__ __forceinline__ float bu2f(u16 v){ return __uint_as_float(((u32)v)<<16); }

// gelu via tanh-form sigmoid: x*sigmoid(1.5957691x + 0.0713548x^3).
__device__ __forceinline__ float geluf(float x){
  float t = x*x;
  float w = x * fmaf(-0.10294453f, t, -2.3022077f);
  float z = exp2f(w);
  return x * __builtin_amdgcn_rcpf(1.f + z);
}
__device__ __forceinline__ float siluf(float x){
  float z = exp2f(-1.442695f * x);
  return x * __builtin_amdgcn_rcpf(1.f + z);
}

__device__ __forceinline__ float wsum(float v){
#pragma unroll
  for (int o=32;o>0;o>>=1) v += __shfl_xor(v,o,64);
  return v;
}
__device__ __forceinline__ float wmax(float v){
#pragma unroll
  for (int o=32;o>0;o>>=1) v = fmaxf(v, __shfl_xor(v,o,64));
  return v;
}
__device__ __forceinline__ void top2(const float* lg, int& i1, int& i2, float& wA){
  i1 = 0; float v1 = lg[0];
#pragma unroll
  for (int e=1;e<8;e++) if (lg[e] > v1){ v1 = lg[e]; i1 = e; }
  i2 = 0; float v2 = -1e30f;
#pragma unroll
  for (int e=0;e<8;e++) if (e != i1 && lg[e] > v2){ v2 = lg[e]; i2 = e; }
  wA = 1.f/(1.f + expf(v2 - v1));
}

// packed 2-value wave reduction: even lanes sum(x), odd lanes sum(x*x).
__device__ __forceinline__ float sum2_wave(float x, int b0){
  float s = x, ss = x*x;
  float v = (b0 ? ss : s) + __shfl_xor(b0 ? s : ss, 1, 64);
  v += __shfl_xor(v, 2, 64);
  v += __shfl_xor(v, 4, 64);
  v += __shfl_xor(v, 8, 64);
  v += __shfl_xor(v, 16, 64);
  v += __shfl_xor(v, 32, 64);
  return v;
}

// 8-value reduce-scatter butterfly: lane l returns full-wave sum of p[l&7].
__device__ __forceinline__ float rsum8(const float p[8], int lane){
  int b0 = lane & 1, b1 = lane & 2, b2 = lane & 4;
  float w[4], u[2], v;
#pragma unroll
  for (int j=0;j<4;j++){
    float keep = b0 ? p[2*j+1] : p[2*j];
    float send = b0 ? p[2*j]   : p[2*j+1];
    w[j] = keep + __shfl_xor(send, 1, 64);
  }
#pragma unroll
  for (int i=0;i<2;i++){
    float keep = b1 ? w[2*i+1] : w[2*i];
    float send = b1 ? w[2*i]   : w[2*i+1];
    u[i] = keep + __shfl_xor(send, 2, 64);
  }
  {
    float keep = b2 ? u[1] : u[0];
    float send = b2 ? u[0] : u[1];
    v = keep + __shfl_xor(send, 4, 64);
  }
  v += __shfl_xor(v, 8, 64);
  v += __shfl_xor(v, 16, 64);
  v += __shfl_xor(v, 32, 64);
  return v;
}

// load short8 fragment from two 8B-aligned LDS halves
__device__ __forceinline__ short8 ld8(const u16* p){
  s16x4 lo = *(const s16x4*)p;
  s16x4 hi = *(const s16x4*)(p + 4);
  short8 r;
  r[0]=lo[0]; r[1]=lo[1]; r[2]=lo[2]; r[3]=lo[3];
  r[4]=hi[0]; r[5]=hi[1]; r[6]=hi[2]; r[7]=hi[3];
  return r;
}

// ---------------- init: zero cnts + body_w softmax ----------------
__global__ __launch_bounds__(64) void k_init(int* cnts, const float* __restrict__ body_w,
                                             float* __restrict__ bwv){
  int t = threadIdx.x;
  cnts[t] = 0;
  if (t < 8){
    float v[8]; float mx = -1e30f;
#pragma unroll
    for (int j=0;j<8;j++){ v[j] = body_w[t*8+j]; mx = fmaxf(mx, v[j]); }
    float s = 0.f;
#pragma unroll
    for (int j=0;j<8;j++){ v[j] = expf(v[j]-mx); s += v[j]; }
#pragma unroll
    for (int j=0;j<8;j++) bwv[t*8+j] = v[j]/s;
  }
}

// ---------------- merged repack: all 6 weight tensors, region-switched ----------------
__global__ __launch_bounds__(256) void k_repack_all(
    const float* __restrict__ s0, u16* __restrict__ d0,
    const float* __restrict__ s1, u16* __restrict__ d1,
    const float* __restrict__ s2, u16* __restrict__ d2,
    const float* __restrict__ s3, u16* __restrict__ d3,
    const float* __restrict__ s4, u16* __restrict__ d4,
    const float* __restrict__ s5, u16* __restrict__ d5){
  long g = (long)blockIdx.x*256 + threadIdx.x;
  if (g >= 4734976) return;
  const float* s; u16* d; int KC, N; long t;
  if      (g < 2097152){ s=s0; d=d0; KC=8;  N=1024; t=g; }
  else if (g < 4194304){ s=s1; d=d1; KC=32; N=256;  t=g-2097152; }
  else if (g < 4325376){ s=s2; d=d2; KC=2;  N=256;  t=g-4194304; }
  else if (g < 4456448){ s=s3; d=d3; KC=8;  N=64;   t=g-4325376; }
  else if (g < 4472832){ s=s4; d=d4; KC=2;  N=256;  t=g-4456448; }
  else                 { s=s5; d=d5; KC=16; N=512;  t=g-4472832; }
  int NT = N >> 4;
  int j = t & 7, n = (t>>3) & 15, q = (t>>7) & 3;
  long r2 = t >> 9;
  int kc = (int)(r2 % KC); long r3 = r2 / KC;
  int nt = (int)(r3 % NT); int e = (int)(r3 / NT);
  int k = kc*32 + q*8 + j;
  d[t] = f2bu(s[((size_t)(e*(KC*32) + k))*N + nt*16 + n]);
}

// ---------------- direct fill: block-aggregated atomic offsets, no scan ----------------
__global__ __launch_bounds__(256) void k_filld(const int2* __restrict__ eidx, int n, int stride,
                                               int* __restrict__ cnt, int* __restrict__ alist){
  __shared__ int lc[8], gb[8], lc2[8];
  int tid = threadIdx.x;
  if (tid < 8){ lc[tid] = 0; lc2[tid] = 0; }
  __syncthreads();
  for (int i = blockIdx.x*256 + tid; i < n; i += gridDim.x*256){
    int2 e = eidx[i];
    atomicAdd(&lc[e.x], 1); atomicAdd(&lc[e.y], 1);
  }
  __syncthreads();
  if (tid < 8) gb[tid] = atomicAdd(&cnt[tid], lc[tid]);
  __syncthreads();
  for (int i = blockIdx.x*256 + tid; i < n; i += gridDim.x*256){
    int2 e = eidx[i];
    int s0 = atomicAdd(&lc2[e.x], 1); alist[e.x*stride + gb[e.x] + s0] = i*2;
    int s1 = atomicAdd(&lc2[e.y], 1); alist[e.y*stride + gb[e.y] + s1] = i*2 + 1;
  }
}

// ---------------- pre: LN + pos + gate ----------------
__global__ __launch_bounds__(256) void k_text_pre(
    const float* __restrict__ xf, const float* __restrict__ tg, const float* __restrict__ tb,
    const float* __restrict__ tpos, const float* __restrict__ gw,
    u16* __restrict__ xtb, int2* __restrict__ eidxT, float2* __restrict__ ewT){
  int tok = blockIdx.x, tid = threadIdx.x;
  int n = tok % 77;
  __shared__ float redw[32], lgs[8];
  int w = tid >> 6, ln = tid & 63;
  int b0 = tid & 1;
  float xv = xf[tok*256 + tid];
  float v = sum2_wave(xv, b0);
  if (ln < 2) redw[w*2 + ln] = v;
  __syncthreads();
  float mean = (redw[0]+redw[2]+redw[4]+redw[6]) * (1.f/256.f);
  float var  = (redw[1]+redw[3]+redw[5]+redw[7]) * (1.f/256.f) - mean*mean;
  float r = rsqrtf(var + 1e-5f);
  float xn = (xv - mean)*r*tg[tid] + tb[tid] + tpos[n*256 + tid];
  xtb[tok*256 + tid] = f2bu(xn);
  float p[8];
#pragma unroll
  for (int e=0;e<8;e++) p[e] = xn * gw[tid*8 + e];
  float vv = rsum8(p, ln);
  __syncthreads();
  if (ln < 8) redw[w*8 + ln] = vv;
  __syncthreads();
  if (tid < 8) lgs[tid] = redw[tid] + redw[8+tid] + redw[16+tid] + redw[24+tid];
  __syncthreads();
  if (tid == 0){
    int i1, i2; float wA; top2(lgs, i1, i2, wA);
    eidxT[tok] = make_int2(i1, i2);
    ewT[tok] = make_float2(wA, 1.f - wA);
  }
}

__global__ __launch_bounds__(256) void k_motion_pre(
    const float* __restrict__ x, const float* __restrict__ ng, const float* __restrict__ nb,
    const float* __restrict__ mpos, const float* __restrict__ gw,
    u16* __restrict__ xmb, int2* __restrict__ eidxM, float2* __restrict__ ewM){
  int tok = blockIdx.x*4 + (threadIdx.x >> 6);
  int d = threadIdx.x & 63;
  int b0 = d & 1;
  float xv = x[(size_t)tok*64 + d];
  float v = sum2_wave(xv, b0);
  float o = __shfl_xor(v, 1, 64);
  float sf  = b0 ? o : v;
  float ssf = b0 ? v : o;
  float mean = sf * (1.f/64.f);
  float var  = ssf * (1.f/64.f) - mean*mean;
  float r = rsqrtf(var + 1e-5f);
  int h = tok & 7; int t = (tok >> 3) & 255;
  float xn = (xv - mean)*r*ng[d] + nb[d] + mpos[(t*8+h)*64 + d];
  xmb[(size_t)tok*64 + d] = f2bu(xn);
  float p[8];
#pragma unroll
  for (int e=0;e<8;e++) p[e] = xn * gw[d*8 + e];
  float vv = rsum8(p, d);
  float lg[8];
#pragma unroll
  for (int e=0;e<8;e++) lg[e] = __shfl(vv, e, 64);
  if (d == 0){
    int i1, i2; float wA; top2(lg, i1, i2, wA);
    eidxM[tok] = make_int2(i1, i2);
    ewM[tok] = make_float2(wA, 1.f - wA);
  }
}

// ---------------- motion MoE v2: r10 block structure, swapped-operand MFMA ----------------
__global__ __launch_bounds__(256, 4) void k_motion_moe(
    const u16* __restrict__ xmb, const int* __restrict__ alistM, const int* __restrict__ cnts,
    const u16* __restrict__ w1pk, const float* __restrict__ fc1b,
    const u16* __restrict__ w2pk, const float* __restrict__ fc2b,
    u16* __restrict__ ycM){
  int e = blockIdx.y, tile = blockIdx.x, tid = threadIdx.x;
  int cnt = cnts[8+e]; int base = tile*32;
  if (base >= cnt) return;
  int nn = min(32, cnt - base); int off = e*131072;
  __shared__ int toks[32];
  __shared__ u16 xs[32*72];
  __shared__ u16 hT[32*264];     // [tok][ch]
  if (tid < 32) toks[tid] = alistM[off + base + min(tid, nn-1)];
  __syncthreads();
  { int row = tid >> 3, c0 = (tid & 7)*8;
    short8 v = *(const short8*)(xmb + (size_t)(toks[row]>>1)*64 + c0);
    *(short8*)&xs[row*72 + c0] = v; }
  __syncthreads();
  int lane = tid & 63, w = tid >> 6;
  int n = lane & 15, q = lane >> 4;
  int mt = w & 1;
  short8 x0 = *(const short8*)&xs[(mt*16 + n)*72 + q*8];
  short8 x1 = *(const short8*)&xs[(mt*16 + n)*72 + 32 + q*8];
  const short8* b1 = (const short8*)(w1pk + (size_t)e*16384);
  short8 b1f[16];
#pragma unroll
  for (int i=0;i<8;i++){
    int nt = (w>>1)*8 + i;
    b1f[2*i]   = b1[(nt*2+0)*64 + lane];
    b1f[2*i+1] = b1[(nt*2+1)*64 + lane];
  }
#pragma unroll
  for (int i=0;i<8;i++){
    int nt = (w>>1)*8 + i;
    f32x4 acc = {0.f,0.f,0.f,0.f};
    acc = MFMA16(b1f[2*i],   x0, acc);
    acc = MFMA16(b1f[2*i+1], x1, acc);
    f32x4 bias = *(const f32x4*)(fc1b + e*256 + nt*16 + q*4);
    s16x4 o;
#pragma unroll
    for (int r=0;r<4;r++) o[r] = (short)f2bu(geluf(acc[r] + bias[r]));
    *(s16x4*)&hT[(mt*16 + n)*264 + nt*16 + q*4] = o;   // b64, [tok][ch]
  }
  __syncthreads();
  short8 a2[8];
#pragma unroll
  for (int kc=0;kc<8;kc++) a2[kc] = *(const short8*)&hT[(mt*16 + n)*264 + kc*32 + q*8];
  const short8* b2 = (const short8*)(w2pk + (size_t)e*16384);
  bool valid = (mt*16 + n) < nn;
  int slot = toks[mt*16 + n];
#pragma unroll
  for (int i=0;i<2;i++){
    int nt = (w>>1)*2 + i;
    f32x4 acc = {0.f,0.f,0.f,0.f};
#pragma unroll
    for (int kc=0;kc<8;kc++) acc = MFMA16(b2[(nt*8+kc)*64 + lane], a2[kc], acc);
    f32x4 bias = *(const f32x4*)(fc2b + e*64 + nt*16 + q*4);
    if (valid){
      s16x4 o;
#pragma unroll
      for (int r=0;r<4;r++) o[r] = (short)f2bu(acc[r] + bias[r]);
      *(s16x4*)(ycM + (size_t)slot*64 + nt*16 + q*4) = o;   // 8B store
    }
  }
}

// ---------------- text MoE (MFMA): 16-token tiles ----------------
__global__ __launch_bounds__(256) void k_text_moe(
    const u16* __restrict__ xtb, const int* __restrict__ alistT, const int* __restrict__ cnts,
    const u16* __restrict__ w1pk, const float* __restrict__ fc1b,
    const u16* __restrict__ w2pk, const float* __restrict__ fc2b,
    float* __restrict__ ycT){
  int e = blockIdx.y, tile = blockIdx.x, tid = threadIdx.x;
  int cnt = cnts[e]; int base = tile*16;
  if (base >= cnt) return;
  int nn = min(16, cnt - base); int off = e*4928;
  __shared__ int toks[16];
  __shared__ u16 xs[16*280];
  __shared__ u16 hT[16*1048];
  if (tid < 16) toks[tid] = alistT[off + base + min(tid, nn-1)];
  __syncthreads();
  { int row = tid >> 4, c0 = (tid & 15)*16;
    const short8* sp = (const short8*)(xtb + (size_t)(toks[row]>>1)*256 + c0);
    short8 v0 = sp[0], v1 = sp[1];
    *(short8*)&xs[row*280 + c0] = v0;
    *(short8*)&xs[row*280 + c0 + 8] = v1; }
  __syncthreads();
  int lane = tid & 63, w = tid >> 6;
  int n = lane & 15, q = lane >> 4;
  short8 a_[8];
#pragma unroll
  for (int kc=0;kc<8;kc++) a_[kc] = *(const short8*)&xs[n*280 + kc*32 + q*8];
  const short8* b1 = (const short8*)(w1pk + (size_t)e*262144);
#pragma unroll 1
  for (int i=0;i<16;i++){
    int nt = w*16 + i;
    f32x4 acc = {0.f,0.f,0.f,0.f};
#pragma unroll
    for (int kc=0;kc<8;kc++) acc = MFMA16(a_[kc], b1[(nt*8+kc)*64 + lane], acc);
    float bias = fc1b[e*1024 + nt*16 + n];
#pragma unroll
    for (int r=0;r<4;r++)
      hT[(q*4 + r)*1048 + nt*16 + n] = f2bu(geluf(acc[r] + bias));
  }
  __syncthreads();
  const short8* b2 = (const short8*)(w2pk + (size_t)e*262144);
  f32x4 acc[4];
#pragma unroll
  for (int i=0;i<4;i++) acc[i] = (f32x4){0.f,0.f,0.f,0.f};
#pragma unroll 1
  for (int kc=0;kc<32;kc++){
    short8 a = *(const short8*)&hT[n*1048 + kc*32 + q*8];
#pragma unroll
    for (int i=0;i<4;i++){
      int nt = w*4 + i;
      acc[i] = MFMA16(a, b2[(nt*32+kc)*64 + lane], acc[i]);
    }
  }
#pragma unroll
  for (int i=0;i<4;i++){
    int nt = w*4 + i;
    float bias = fc2b[e*256 + nt*16 + n];
#pragma unroll
    for (int r=0;r<4;r++){
      int row = q*4 + r;
      if (row < nn) ycT[(size_t)toks[row]*256 + nt*16 + n] = acc[i][r] + bias;
    }
  }
}

// combine 2 expert contributions (gate-weighted), gelu, proj 256->128 -> tfeat
__global__ __launch_bounds__(128) void k_text_combine(
    const float* __restrict__ ycT, const float2* __restrict__ ewT,
    const float* __restrict__ pw, const float* __restrict__ pb,
    float* __restrict__ tfeat){
  int t = blockIdx.x, tid = threadIdx.x;
  __shared__ float gy[256];
  float2 w = ewT[t];
  for (int c=tid; c<256; c+=128){
    float y = w.x*ycT[(size_t)(t*2)*256 + c] + w.y*ycT[(size_t)(t*2+1)*256 + c];
    gy[c] = geluf(y);
  }
  __syncthreads();
  float a = pb[tid];
  for (int k=0;k<256;k++) a += gy[k] * pw[k*128 + tid];
  tfeat[(size_t)t*128 + tid] = a;
}

// motion combine + gelu + proj 64->256 (MFMA) -> mf bf16, fused q-softmax.
__global__ __launch_bounds__(256) void k_mproj(
    const u16* __restrict__ ycM, const float2* __restrict__ ewM,
    const u16* __restrict__ wpk, const float* __restrict__ pb,
    u16* __restrict__ mf, u16* __restrict__ qs){
  int t0 = blockIdx.x*32, tid = threadIdx.x;
  __shared__ u16 xs[32*72];
  { int row = tid >> 3, c0 = (tid & 7)*8;
    int tok = t0 + row;
    float2 wgt = ewM[tok];
    short8 v0 = *(const short8*)(ycM + (size_t)(tok*2)*64 + c0);
    short8 v1 = *(const short8*)(ycM + (size_t)(tok*2+1)*64 + c0);
    short8 o;
#pragma unroll
    for (int j=0;j<8;j++)
      o[j] = (short)f2bu(geluf(wgt.x*bu2f((u16)v0[j]) + wgt.y*bu2f((u16)v1[j])));
    *(short8*)&xs[row*72 + c0] = o; }
  __syncthreads();
  int lane = tid & 63, w = tid >> 6;
  int n = lane & 15, q = lane >> 4;
  int mt = w & 1;
  short8 a0 = *(const short8*)&xs[(mt*16 + n)*72 + q*8];
  short8 a1 = *(const short8*)&xs[(mt*16 + n)*72 + 32 + q*8];
  const short8* bp = (const short8*)wpk;
  float vals[4][4];   // [nt-12][r], only waves 2,3
#pragma unroll
  for (int i=0;i<8;i++){
    int nt = (w>>1)*8 + i;
    f32x4 acc = {0.f,0.f,0.f,0.f};
    acc = MFMA16(a0, bp[(nt*2+0)*64 + lane], acc);
    acc = MFMA16(a1, bp[(nt*2+1)*64 + lane], acc);
    float bias = pb[nt*16 + n];
#pragma unroll
    for (int r=0;r<4;r++){
      float v = acc[r] + bias;
      if (w >= 2 && i >= 4) vals[i-4][r] = v;
      int tok = t0 + mt*16 + q*4 + r;
      mf[(size_t)tok*256 + nt*16 + n] = f2bu(v);
    }
  }
  if (w >= 2){
#pragma unroll
    for (int r=0;r<4;r++){
      int tok = t0 + mt*16 + q*4 + r;
      float m = fmaxf(fmaxf(vals[0][r], vals[1][r]), fmaxf(vals[2][r], vals[3][r]));
#pragma unroll
      for (int o=8;o>0;o>>=1) m = fmaxf(m, __shfl_xor(m, o, 64));
      float e0 = expf(vals[0][r]-m), e1 = expf(vals[1][r]-m);
      float e2 = expf(vals[2][r]-m), e3 = expf(vals[3][r]-m);
      float s = (e0+e1) + (e2+e3);
#pragma unroll
      for (int o=8;o>0;o>>=1) s += __shfl_xor(s, o, 64);
      float inv = __builtin_amdgcn_rcpf(s);
      u16* qp = qs + (size_t)tok*64 + n;
      qp[0]  = f2bu(e0*inv);
      qp[16] = f2bu(e1*inv);
      qp[32] = f2bu(e2*inv);
      qp[48] = f2bu(e3*inv);
    }
  }
}

// ---------------- eo = silu(emb) @ (2048x1024) + b : split-K tiled f32 ----------------
__global__ __launch_bounds__(256) void k_eo1(const float* __restrict__ emb, const float* __restrict__ ew,
                      float* __restrict__ ep){
  int ct = blockIdx.x & 15;
  int ks = blockIdx.x >> 4;
  int tid = threadIdx.x;
  int k0 = ks*128, c0 = ct*64;
  __shared__ float aS[128*68];
  __shared__ float bS[128*64];
#pragma unroll
  for (int i=0;i<8;i++){
    int idx4 = tid + i*256;
    int b = idx4 >> 5, kq = idx4 & 31;
    f32x4 v = *(const f32x4*)(emb + (size_t)b*2048 + k0 + kq*4);
    aS[(kq*4+0)*68 + b] = siluf(v[0]);
    aS[(kq*4+1)*68 + b] = siluf(v[1]);
    aS[(kq*4+2)*68 + b] = siluf(v[2]);
    aS[(kq*4+3)*68 + b] = siluf(v[3]);
  }
#pragma unroll
  for (int i=0;i<8;i++){
    int idx4 = tid + i*256;
    int kk = idx4 >> 4, cq = idx4 & 15;
    *(f32x4*)&bS[kk*64 + cq*4] = *(const f32x4*)(ew + (size_t)(k0+kk)*1024 + c0 + cq*4);
  }
  __syncthreads();
  int cg = tid & 15, bg = tid >> 4;
  f32x4 acc[4] = {{0.f,0.f,0.f,0.f},{0.f,0.f,0.f,0.f},{0.f,0.f,0.f,0.f},{0.f,0.f,0.f,0.f}};
#pragma unroll 4
  for (int kk=0;kk<128;kk++){
    f32x4 a = *(const f32x4*)&aS[kk*68 + bg*4];
    f32x4 bb = *(const f32x4*)&bS[kk*64 + cg*4];
#pragma unroll
    for (int i=0;i<4;i++){
      acc[i][0] += a[i]*bb[0];
      acc[i][1] += a[i]*bb[1];
      acc[i][2] += a[i]*bb[2];
      acc[i][3] += a[i]*bb[3];
    }
  }
#pragma unroll
  for (int i=0;i<4;i++){
    int b = bg*4 + i;
    *(f32x4*)&ep[((size_t)(ks*64 + b))*1024 + c0 + cg*4] = acc[i];
  }
}

__global__ __launch_bounds__(256) void k_eo2(const float* __restrict__ ep, const float* __restrict__ ebias,
                      float* __restrict__ eo){
  int idx = blockIdx.x*256 + threadIdx.x;
  int c = idx & 1023;
  float s = ebias[c];
#pragma unroll
  for (int ks=0;ks<16;ks++) s += ep[(size_t)ks*65536 + idx];
  eo[idx] = s;
}

// ---------------- attention: single-pass LDS-resident, MFMA PV ----------------
#define AT_STRIDE 364
__global__ __launch_bounds__(512) void k_attn(const float* __restrict__ tfeat, const u16* __restrict__ mf,
                       const float* __restrict__ src_mask, const int* __restrict__ cond,
                       u16* __restrict__ attnT){
  int b = blockIdx.x >> 3; int h = blockIdx.x & 7;
  int tid = threadIdx.x; int c = tid & 63; int part = tid >> 6;
  __shared__ u16 ebT[64*AT_STRIDE];
  __shared__ u16 vbT[64*AT_STRIDE];
  __shared__ float colmax[64], colsum[64], red[512];
  float tc = ((cond[b] % 10) > 0) ? 1.f : 0.f;
  float negt = (1.f - tc) * (-1e6f);

  float mx = -1e30f;
  for (int k = 0; k < 11; k++){
    int n0 = part*44 + k*4;
    s16x4 kb4, vb4;
#pragma unroll
    for (int jj = 0; jj < 4; jj++){
      int n = n0 + jj;
      float kv, vv;
      if (n < 77){
        const float* trow = tfeat + (b*77+n)*128;
        kv = trow[c] + negt;
        vv = trow[64 + c] * tc;
      } else if (n < 333){
        int t = n - 77; float smv = src_mask[b*256 + t];
        const u16* mrow = mf + ((size_t)(b*256+t)*8+h)*256;
        kv = bu2f(mrow[64 + c]) + (1.f - smv)*(-1e6f);
        vv = bu2f(mrow[128 + c]) * smv;
      } else { kv = -1e30f; vv = 0.f; }
      kb4[jj] = (short)f2bu(kv);
      vb4[jj] = (short)f2bu(vv);
      mx = fmaxf(mx, kv);
    }
    *(s16x4*)&ebT[c*AT_STRIDE + n0] = kb4;
    *(s16x4*)&vbT[c*AT_STRIDE + n0] = vb4;
  }
  red[tid] = mx; __syncthreads();
  if (part == 0){
    float m = red[c];
#pragma unroll
    for (int p=1;p<8;p++) m = fmaxf(m, red[p*64 + c]);
    colmax[c] = m;
  }
  __syncthreads();
  { int rowc = tid >> 3, j = tid & 7;
    float cm = colmax[rowc];
    float s = 0.f;
    for (int k = 0; k < 11; k++){
      int n0 = (j*11 + k)*4;
      s16x4 v4 = *(const s16x4*)&ebT[rowc*AT_STRIDE + n0];
      float e0 = expf(bu2f((u16)v4[0]) - cm);
      float e1 = expf(bu2f((u16)v4[1]) - cm);
      float e2 = expf(bu2f((u16)v4[2]) - cm);
      float e3 = expf(bu2f((u16)v4[3]) - cm);
      s += (e0+e1) + (e2+e3);
      s16x4 o;
      o[0]=(short)f2bu(e0); o[1]=(short)f2bu(e1); o[2]=(short)f2bu(e2); o[3]=(short)f2bu(e3);
      *(s16x4*)&ebT[rowc*AT_STRIDE + n0] = o;
    }
    red[tid] = s;
  }
  __syncthreads();
  if (tid < 64){
    float t2 = 0.f;
#pragma unroll
    for (int p=0;p<8;p++) t2 += red[tid*8 + p];
    colsum[tid] = t2;
  }
  __syncthreads();
  int lane = tid & 63, w = tid >> 6;
  int n16 = lane & 15, q = lane >> 4;
  int mt = w >> 1;
  int ntb = (w & 1) * 2;
  f32x4 acc0 = {0.f,0.f,0.f,0.f}, acc1 = {0.f,0.f,0.f,0.f};
  const u16* ea = &ebT[(mt*16 + n16)*AT_STRIDE + q*8];
  const u16* v0p = &vbT[(ntb*16 + n16)*AT_STRIDE + q*8];
  const u16* v1p = &vbT[((ntb+1)*16 + n16)*AT_STRIDE + q*8];
#pragma unroll
  for (int kc = 0; kc < 11; kc++){
    short8 a  = ld8(ea  + kc*32);
    short8 b0 = ld8(v0p + kc*32);
    short8 b1 = ld8(v1p + kc*32);
    acc0 = MFMA16(a, b0, acc0);
    acc1 = MFMA16(a, b1, acc1);
  }
  float inv[4];
#pragma unroll
  for (int r=0;r<4;r++) inv[r] = __builtin_amdgcn_rcpf(colsum[mt*16 + q*4 + r]);
  u16* outp = attnT + (size_t)(b*8+h)*4096;
  int d0 = mt*16 + q*4;
  {
    int l = ntb*16 + n16;
    s16x4 o;
#pragma unroll
    for (int r=0;r<4;r++) o[r] = (short)f2bu(acc0[r]*inv[r]);
    *(s16x4*)(outp + l*64 + d0) = o;
  }
  {
    int l = (ntb+1)*16 + n16;
    s16x4 o;
#pragma unroll
    for (int r=0;r<4;r++) o[r] = (short)f2bu(acc1[r]*inv[r]);
    *(s16x4*)(outp + l*64 + d0) = o;
  }
}

// ---------------- y_t = qs @ attn per (b,h): M=256,K=64,N=64 MFMA ----------------
__global__ __launch_bounds__(256) void k_yt(const u16* __restrict__ qs, const u16* __restrict__ attnT,
                                            u16* __restrict__ yt){
  int b = blockIdx.x >> 3; int h = blockIdx.x & 7;
  int tid = threadIdx.x;
  int lane = tid & 63, w = tid >> 6;
  int n = lane & 15, q = lane >> 4;
  const u16* qsb = qs + ((size_t)(b*256)*8 + h)*64;
  const u16* ab  = attnT + (size_t)(b*8+h)*4096;
  f32x4 acc[4][4];
#pragma unroll
  for (int mt=0;mt<4;mt++)
#pragma unroll
    for (int nt=0;nt<4;nt++) acc[mt][nt] = (f32x4){0.f,0.f,0.f,0.f};
#pragma unroll
  for (int kc=0;kc<2;kc++){
    short8 a_[4], b_[4];
#pragma unroll
    for (int mt=0;mt<4;mt++){
      int t = w*64 + mt*16 + n;
      a_[mt] = *(const short8*)(qsb + (size_t)t*512 + kc*32 + q*8);
    }
#pragma unroll
    for (int nt=0;nt<4;nt++){
      int l = nt*16 + n;
      b_[nt] = *(const short8*)(ab + l*64 + kc*32 + q*8);
    }
#pragma unroll
    for (int mt=0;mt<4;mt++)
#pragma unroll
      for (int nt=0;nt<4;nt++)
        acc[mt][nt] = MFMA16(a_[mt], b_[nt], acc[mt][nt]);
  }
#pragma unroll
  for (int mt=0;mt<4;mt++)
#pragma unroll
    for (int nt=0;nt<4;nt++){
      int l = nt*16 + n;
#pragma unroll
      for (int r=0;r<4;r++){
        int t = w*64 + mt*16 + q*4 + r;
        yt[((size_t)(b*256+t)*8 + h)*64 + l] = f2bu(acc[mt][nt][r]);
      }
    }
}

// ---------------- j2: body mix + y_t, LN(512), modulate, silu -> sbuf ----------------
__global__ __launch_bounds__(256) void k_j2(const u16* __restrict__ mf, const u16* __restrict__ yt,
                     const float* __restrict__ bwv, const float* __restrict__ eo,
                     const float* __restrict__ sb_ng, const float* __restrict__ sb_nb,
                     float* __restrict__ sbuf){
  int blk = blockIdx.x; int b = blk >> 8; int t = blk & 255;
  int tid = threadIdx.x;
  __shared__ float mfl[512], red[4];
#pragma unroll
  for (int ii=0; ii<2; ii++){
    int idx = tid + ii*256; int h = idx >> 6; int dd = idx & 63;
    mfl[idx] = bu2f(mf[((size_t)(b*256+t)*8+h)*256 + dd]);
  }
  __syncthreads();
  int w = tid >> 6, ln = tid & 63;
  float out[2];
#pragma unroll
  for (int ii=0; ii<2; ii++){
    int idx = tid + ii*256; int h = idx >> 6; int l = idx & 63;
    float a = bu2f(yt[((size_t)(b*256+t)*8 + h)*64 + l]);
    float bs = 0.f;
#pragma unroll
    for (int lh=0; lh<8; lh++) bs += bwv[h*8 + lh] * mfl[lh*64 + l];
    out[ii] = a + bs;
  }
  float psum = wsum(out[0] + out[1]);
  if (ln == 0) red[w] = psum;
  __syncthreads();
  float mean = (red[0]+red[1]+red[2]+red[3]) * (1.f/512.f);
  __syncthreads();
  float c0 = out[0]-mean, c1 = out[1]-mean;
  float pv = wsum(c0*c0 + c1*c1);
  if (ln == 0) red[w] = pv;
  __syncthreads();
  float var = (red[0]+red[1]+red[2]+red[3]) * (1.f/512.f);
  float r = rsqrtf(var + 1e-5f);
#pragma unroll
  for (int ii=0; ii<2; ii++){
    int c = tid + ii*256;
    float hn = (out[ii]-mean)*r*sb_ng[c] + sb_nb[c];
    float e1 = eo[b*1024 + c], e2 = eo[b*1024 + 512 + c];
    float hm = hn*(1.f + e1) + e2;
    sbuf[(size_t)blk*512 + c] = siluf(hm);
  }
}

// ---------------- out = x + sbuf @ W + b (MFMA, 32-row tiles, in-place d_out) ----------------
__global__ __launch_bounds__(256) void k_out(const u16* __restrict__ wpk,
                      const float* __restrict__ bias, const float* __restrict__ x,
                      float* __restrict__ out){
  int r0 = blockIdx.x*32, tid = threadIdx.x;
  __shared__ u16 xs[32*536];
  { int row = tid >> 3, c0 = (tid & 7)*64;
    const f32x4* sp = (const f32x4*)(out + (size_t)(r0+row)*512 + c0);
#pragma unroll
    for (int j=0;j<8;j++){
      f32x4 va = sp[2*j], vb = sp[2*j+1];
      short8 o;
      o[0]=(short)f2bu(va[0]); o[1]=(short)f2bu(va[1]); o[2]=(short)f2bu(va[2]); o[3]=(short)f2bu(va[3]);
      o[4]=(short)f2bu(vb[0]); o[5]=(short)f2bu(vb[1]); o[6]=(short)f2bu(vb[2]); o[7]=(short)f2bu(vb[3]);
      *(short8*)&xs[row*536 + c0 + 8*j] = o;
    } }
  __syncthreads();
  int lane = tid & 63, w = tid >> 6;
  int n = lane & 15, q = lane >> 4;
  int mt = w & 1;
  short8 a_[16];
#pragma unroll
  for (int kc=0;kc<16;kc++) a_[kc] = *(const short8*)&xs[(mt*16 + n)*536 + kc*32 + q*8];
  const short8* bp = (const short8*)wpk;
#pragma unroll 1
  for (int i=0;i<16;i++){
    int nt = (w>>1)*16 + i;
    f32x4 acc = {0.f,0.f,0.f,0.f};
#pragma unroll
    for (int kc=0;kc<16;kc++) acc = MFMA16(a_[kc], bp[(nt*16+kc)*64 + lane], acc);
    int col = nt*16 + n;
    float bv = bias[col];
#pragma unroll
    for (int r=0;r<4;r++){
      size_t rowg = (size_t)(r0 + mt*16 + q*4 + r);
      out[rowg*512 + col] = acc[r] + bv + x[rowg*512 + col];
    }
  }
}

extern "C" void kernel_launch(void* const* d_in, const int* in_sizes, int n_in,
                              void* d_out, int out_size, void* d_ws, size_t ws_size,
                              hipStream_t stream) {
  (void)in_sizes; (void)n_in; (void)out_size; (void)ws_size;
  const float* x        = (const float*)d_in[0];
  const float* xf       = (const float*)d_in[1];
  const float* emb      = (const float*)d_in[2];
  const float* src_mask = (const float*)d_in[3];
  const float* norm_g   = (const float*)d_in[4];
  const float* norm_b   = (const float*)d_in[5];
  const float* tnorm_g  = (const float*)d_in[6];
  const float* tnorm_b  = (const float*)d_in[7];
  const float* m_pos    = (const float*)d_in[8];
  const float* m_gate   = (const float*)d_in[9];
  const float* m_fc1w   = (const float*)d_in[10];
  const float* m_fc1b   = (const float*)d_in[11];
  const float* m_fc2w   = (const float*)d_in[12];
  const float* m_fc2b   = (const float*)d_in[13];
  const float* m_projw  = (const float*)d_in[14];
  const float* m_projb  = (const float*)d_in[15];
  const float* t_pos    = (const float*)d_in[16];
  const float* t_gate   = (const float*)d_in[17];
  const float* t_fc1w   = (const float*)d_in[18];
  const float* t_fc1b   = (const float*)d_in[19];
  const float* t_fc2w   = (const float*)d_in[20];
  const float* t_fc2b   = (const float*)d_in[21];
  const float* t_projw  = (const float*)d_in[22];
  const float* t_projb  = (const float*)d_in[23];
  const float* body_w   = (const float*)d_in[24];
  const float* sb_embw  = (const float*)d_in[25];
  const float* sb_embb  = (const float*)d_in[26];
  const float* sb_ng    = (const float*)d_in[27];
  const float* sb_nb    = (const float*)d_in[28];
  const float* sb_outw  = (const float*)d_in[29];
  const float* sb_outb  = (const float*)d_in[30];
  const int*   cond     = (const int*)d_in[31];

  // ---- workspace (~136 MB), manual lifetime aliasing ----
  char* base = (char*)d_ws;
  size_t o = 0;
  auto alloc = [&](size_t bytes)->char*{ char* r = base + o; o += (bytes + 255) & ~(size_t)255; return r; };
  u16*  mf      = (u16*)alloc(67108864);    // motion_feat bf16, live to end
  char* R       = alloc(33554432);          // aliased region
  float* ep     = (float*)(R);              // eo partials, dead before xtb use
  u16*  xtb     = (u16*)(R);                // dead after k_text_moe
  float* ycT    = (float*)(R + 4194304);    // dead after k_text_combine
  u16*  ycM     = (u16*)(R);                // dead after k_mproj
  u16*  attnT   = (u16*)(R);                // written after ycM dead
  u16*  yt      = (u16*)(R + 8388608);
  u16*  xmb     = (u16*)alloc(16777216);    // dead after k_motion_moe
  u16*  qs      = xmb;                      // reuses xmb space (written in k_mproj)
  u16*  t1pk    = (u16*)alloc(4194304);
  u16*  t2pk    = (u16*)alloc(4194304);
  u16*  m1pk    = (u16*)alloc(262144);
  u16*  m2pk    = (u16*)alloc(262144);
  u16*  mppk    = (u16*)alloc(32768);
  u16*  wopk    = (u16*)alloc(524288);
  int2* eidxT   = (int2*)alloc(39424);
  float2* ewT   = (float2*)alloc(39424);
  int2* eidxM   = (int2*)alloc(1048576);
  float2* ewM   = (float2*)alloc(1048576);
  int*  alistT  = (int*)alloc(157696);      // [8][4928] strided
  int*  alistM  = (int*)alloc(4194304);     // [8][131072] strided
  int*  cnts    = (int*)alloc(256);
  float* tfeat  = (float*)alloc(2523136);
  float* eo     = (float*)alloc(262144);
  float* bwv    = (float*)alloc(256);
  float* sbuf   = (float*)d_out;

  // setup (merged): init + one repack + eo GEMM
  k_init<<<1, 64, 0, stream>>>(cnts, body_w, bwv);
  k_repack_all<<<18496, 256, 0, stream>>>(t_fc1w, t1pk, t_fc2w, t2pk, m_fc1w, m1pk,
                                          m_fc2w, m2pk, m_projw, mppk, sb_outw, wopk);
  k_eo1<<<256, 256, 0, stream>>>(emb, sb_embw, ep);
  k_eo2<<<256, 256, 0, stream>>>(ep, sb_embb, eo);

  // pre + direct routing (no count/scan)
  k_text_pre<<<4928, 256, 0, stream>>>(xf, tnorm_g, tnorm_b, t_pos, t_gate, xtb, eidxT, ewT);
  k_motion_pre<<<32768, 256, 0, stream>>>(x, norm_g, norm_b, m_pos, m_gate, xmb, eidxM, ewM);
  k_filld<<<32, 256, 0, stream>>>(eidxT, 4928, 4928, cnts, alistT);
  k_filld<<<256, 256, 0, stream>>>(eidxM, 131072, 131072, cnts + 8, alistM);

  // text MoE (MFMA) then combine
  k_text_moe<<<dim3(308, 8), 256, 0, stream>>>(xtb, alistT, cnts, t1pk, t_fc1b, t2pk, t_fc2b, ycT);
  k_text_combine<<<4928, 128, 0, stream>>>(ycT, ewT, t_projw, t_projb, tfeat);

  // motion MoE v2 then combine+proj (fused q-softmax)
  k_motion_moe<<<dim3(4096, 8), 256, 0, stream>>>(xmb, alistM, cnts, m1pk, m_fc1b, m2pk, m_fc2b, ycM);
  k_mproj<<<4096, 256, 0, stream>>>(ycM, ewM, mppk, m_projb, mf, qs);

  // attention + epilogue
  k_attn<<<512, 512, 0, stream>>>(tfeat, mf, src_mask, cond, attnT);
  k_yt<<<512, 256, 0, stream>>>(qs, attnT, yt);
  k_j2<<<16384, 256, 0, stream>>>(mf, yt, bwv, eo, sb_ng, sb_nb, sbuf);
  k_out<<<512, 256, 0, stream>>>(wopk, sb_outb, x, (float*)d_out);
}

// Round 11
// 475.252 us; speedup vs baseline: 1.3854x; 1.0006x over previous
//
#include <hip/hip_runtime.h>
#include <hip/hip_bf16.h>

// STMA block, MI355X. Round 16: cross-kernel fusion. k_yt folded into k_attn
// (attnT stays in LDS, stride-76 bank spread; kills 8MB round-trip + launch).
// k_j2 folded into k_out staging (body-mix + LN + modulate + silu computed
// inline from mf/yt; kills 64MB sbuf round-trip + launch). 16 -> 14 launches.
// k_motion_moe frozen at its structure-invariant ~62us floor.

typedef __hip_bfloat16 bf16;
typedef unsigned short u16;
typedef unsigned int   u32;
typedef __attribute__((ext_vector_type(8))) short short8;   // 8 bf16 = 4 VGPR
typedef __attribute__((ext_vector_type(4))) short s16x4;    // 4 bf16 = 2 VGPR
typedef __attribute__((ext_vector_type(4))) float f32x4;    // MFMA C/D

#define MFMA16(a,b,c) __builtin_amdgcn_mfma_f32_16x16x32_bf16(a,b,c,0,0,0)

__device__ __forceinline__ float b2f(bf16 v){ return __bfloat162float(v); }
__device__ __forceinline__ u16 f2bu(float f){
  union { __hip_bfloat16 hh; u16 us; } cv; cv.hh = __float2bfloat16(f); return cv.us;
}
__device__ __forceinline__ float bu2f(u16 v){ return __uint_as_float(((u32)v)<<16); }

// gelu via tanh-form sigmoid: x*sigmoid(1.5957691x + 0.0713548x^3).
__device__ __forceinline__ float geluf(float x){
  float t = x*x;
  float w = x * fmaf(-0.10294453f, t, -2.3022077f);
  float z = exp2f(w);
  return x * __builtin_amdgcn_rcpf(1.f + z);
}
__device__ __forceinline__ float siluf(float x){
  float z = exp2f(-1.442695f * x);
  return x * __builtin_amdgcn_rcpf(1.f + z);
}

__device__ __forceinline__ float wsum(float v){
#pragma unroll
  for (int o=32;o>0;o>>=1) v += __shfl_xor(v,o,64);
  return v;
}
__device__ __forceinline__ void top2(const float* lg, int& i1, int& i2, float& wA){
  i1 = 0; float v1 = lg[0];
#pragma unroll
  for (int e=1;e<8;e++) if (lg[e] > v1){ v1 = lg[e]; i1 = e; }
  i2 = 0; float v2 = -1e30f;
#pragma unroll
  for (int e=0;e<8;e++) if (e != i1 && lg[e] > v2){ v2 = lg[e]; i2 = e; }
  wA = 1.f/(1.f + expf(v2 - v1));
}

// packed 2-value wave reduction: even lanes sum(x), odd lanes sum(x*x).
__device__ __forceinline__ float sum2_wave(float x, int b0){
  float s = x, ss = x*x;
  float v = (b0 ? ss : s) + __shfl_xor(b0 ? s : ss, 1, 64);
  v += __shfl_xor(v, 2, 64);
  v += __shfl_xor(v, 4, 64);
  v += __shfl_xor(v, 8, 64);
  v += __shfl_xor(v, 16, 64);
  v += __shfl_xor(v, 32, 64);
  return v;
}

// 8-value reduce-scatter butterfly: lane l returns full-wave sum of p[l&7].
__device__ __forceinline__ float rsum8(const float p[8], int lane){
  int b0 = lane & 1, b1 = lane & 2, b2 = lane & 4;
  float w[4], u[2], v;
#pragma unroll
  for (int j=0;j<4;j++){
    float keep = b0 ? p[2*j+1] : p[2*j];
    float send = b0 ? p[2*j]   : p[2*j+1];
    w[j] = keep + __shfl_xor(send, 1, 64);
  }
#pragma unroll
  for (int i=0;i<2;i++){
    float keep = b1 ? w[2*i+1] : w[2*i];
    float send = b1 ? w[2*i]   : w[2*i+1];
    u[i] = keep + __shfl_xor(send, 2, 64);
  }
  {
    float keep = b2 ? u[1] : u[0];
    float send = b2 ? u[0] : u[1];
    v = keep + __shfl_xor(send, 4, 64);
  }
  v += __shfl_xor(v, 8, 64);
  v += __shfl_xor(v, 16, 64);
  v += __shfl_xor(v, 32, 64);
  return v;
}

// load short8 fragment from two 8B-aligned LDS halves
__device__ __forceinline__ short8 ld8(const u16* p){
  s16x4 lo = *(const s16x4*)p;
  s16x4 hi = *(const s16x4*)(p + 4);
  short8 r;
  r[0]=lo[0]; r[1]=lo[1]; r[2]=lo[2]; r[3]=lo[3];
  r[4]=hi[0]; r[5]=hi[1]; r[6]=hi[2]; r[7]=hi[3];
  return r;
}

// ---------------- init: zero cnts + body_w softmax ----------------
__global__ __launch_bounds__(64) void k_init(int* cnts, const float* __restrict__ body_w,
                                             float* __restrict__ bwv){
  int t = threadIdx.x;
  cnts[t] = 0;
  if (t < 8){
    float v[8]; float mx = -1e30f;
#pragma unroll
    for (int j=0;j<8;j++){ v[j] = body_w[t*8+j]; mx = fmaxf(mx, v[j]); }
    float s = 0.f;
#pragma unroll
    for (int j=0;j<8;j++){ v[j] = expf(v[j]-mx); s += v[j]; }
#pragma unroll
    for (int j=0;j<8;j++) bwv[t*8+j] = v[j]/s;
  }
}

// ---------------- merged repack: all 6 weight tensors, region-switched ----------------
__global__ __launch_bounds__(256) void k_repack_all(
    const float* __restrict__ s0, u16* __restrict__ d0,
    const float* __restrict__ s1, u16* __restrict__ d1,
    const float* __restrict__ s2, u16* __restrict__ d2,
    const float* __restrict__ s3, u16* __restrict__ d3,
    const float* __restrict__ s4, u16* __restrict__ d4,
    const float* __restrict__ s5, u16* __restrict__ d5){
  long g = (long)blockIdx.x*256 + threadIdx.x;
  if (g >= 4734976) return;
  const float* s; u16* d; int KC, N; long t;
  if      (g < 2097152){ s=s0; d=d0; KC=8;  N=1024; t=g; }
  else if (g < 4194304){ s=s1; d=d1; KC=32; N=256;  t=g-2097152; }
  else if (g < 4325376){ s=s2; d=d2; KC=2;  N=256;  t=g-4194304; }
  else if (g < 4456448){ s=s3; d=d3; KC=8;  N=64;   t=g-4325376; }
  else if (g < 4472832){ s=s4; d=d4; KC=2;  N=256;  t=g-4456448; }
  else                 { s=s5; d=d5; KC=16; N=512;  t=g-4472832; }
  int NT = N >> 4;
  int j = t & 7, n = (t>>3) & 15, q = (t>>7) & 3;
  long r2 = t >> 9;
  int kc = (int)(r2 % KC); long r3 = r2 / KC;
  int nt = (int)(r3 % NT); int e = (int)(r3 / NT);
  int k = kc*32 + q*8 + j;
  d[t] = f2bu(s[((size_t)(e*(KC*32) + k))*N + nt*16 + n]);
}

// ---------------- direct fill: block-aggregated atomic offsets, no scan ----------------
__global__ __launch_bounds__(256) void k_filld(const int2* __restrict__ eidx, int n, int stride,
                                               int* __restrict__ cnt, int* __restrict__ alist){
  __shared__ int lc[8], gb[8], lc2[8];
  int tid = threadIdx.x;
  if (tid < 8){ lc[tid] = 0; lc2[tid] = 0; }
  __syncthreads();
  for (int i = blockIdx.x*256 + tid; i < n; i += gridDim.x*256){
    int2 e = eidx[i];
    atomicAdd(&lc[e.x], 1); atomicAdd(&lc[e.y], 1);
  }
  __syncthreads();
  if (tid < 8) gb[tid] = atomicAdd(&cnt[tid], lc[tid]);
  __syncthreads();
  for (int i = blockIdx.x*256 + tid; i < n; i += gridDim.x*256){
    int2 e = eidx[i];
    int s0 = atomicAdd(&lc2[e.x], 1); alist[e.x*stride + gb[e.x] + s0] = i*2;
    int s1 = atomicAdd(&lc2[e.y], 1); alist[e.y*stride + gb[e.y] + s1] = i*2 + 1;
  }
}

// ---------------- pre: LN + pos + gate ----------------
__global__ __launch_bounds__(256) void k_text_pre(
    const float* __restrict__ xf, const float* __restrict__ tg, const float* __restrict__ tb,
    const float* __restrict__ tpos, const float* __restrict__ gw,
    u16* __restrict__ xtb, int2* __restrict__ eidxT, float2* __restrict__ ewT){
  int tok = blockIdx.x, tid = threadIdx.x;
  int n = tok % 77;
  __shared__ float redw[32], lgs[8];
  int w = tid >> 6, ln = tid & 63;
  int b0 = tid & 1;
  float xv = xf[tok*256 + tid];
  float v = sum2_wave(xv, b0);
  if (ln < 2) redw[w*2 + ln] = v;
  __syncthreads();
  float mean = (redw[0]+redw[2]+redw[4]+redw[6]) * (1.f/256.f);
  float var  = (redw[1]+redw[3]+redw[5]+redw[7]) * (1.f/256.f) - mean*mean;
  float r = rsqrtf(var + 1e-5f);
  float xn = (xv - mean)*r*tg[tid] + tb[tid] + tpos[n*256 + tid];
  xtb[tok*256 + tid] = f2bu(xn);
  float p[8];
#pragma unroll
  for (int e=0;e<8;e++) p[e] = xn * gw[tid*8 + e];
  float vv = rsum8(p, ln);
  __syncthreads();
  if (ln < 8) redw[w*8 + ln] = vv;
  __syncthreads();
  if (tid < 8) lgs[tid] = redw[tid] + redw[8+tid] + redw[16+tid] + redw[24+tid];
  __syncthreads();
  if (tid == 0){
    int i1, i2; float wA; top2(lgs, i1, i2, wA);
    eidxT[tok] = make_int2(i1, i2);
    ewT[tok] = make_float2(wA, 1.f - wA);
  }
}

__global__ __launch_bounds__(256) void k_motion_pre(
    const float* __restrict__ x, const float* __restrict__ ng, const float* __restrict__ nb,
    const float* __restrict__ mpos, const float* __restrict__ gw,
    u16* __restrict__ xmb, int2* __restrict__ eidxM, float2* __restrict__ ewM){
  int tok = blockIdx.x*4 + (threadIdx.x >> 6);
  int d = threadIdx.x & 63;
  int b0 = d & 1;
  float xv = x[(size_t)tok*64 + d];
  float v = sum2_wave(xv, b0);
  float o = __shfl_xor(v, 1, 64);
  float sf  = b0 ? o : v;
  float ssf = b0 ? v : o;
  float mean = sf * (1.f/64.f);
  float var  = ssf * (1.f/64.f) - mean*mean;
  float r = rsqrtf(var + 1e-5f);
  int h = tok & 7; int t = (tok >> 3) & 255;
  float xn = (xv - mean)*r*ng[d] + nb[d] + mpos[(t*8+h)*64 + d];
  xmb[(size_t)tok*64 + d] = f2bu(xn);
  float p[8];
#pragma unroll
  for (int e=0;e<8;e++) p[e] = xn * gw[d*8 + e];
  float vv = rsum8(p, d);
  float lg[8];
#pragma unroll
  for (int e=0;e<8;e++) lg[e] = __shfl(vv, e, 64);
  if (d == 0){
    int i1, i2; float wA; top2(lg, i1, i2, wA);
    eidxM[tok] = make_int2(i1, i2);
    ewM[tok] = make_float2(wA, 1.f - wA);
  }
}

// ---------------- motion MoE v2: r10 block structure, swapped-operand MFMA ----------------
__global__ __launch_bounds__(256, 4) void k_motion_moe(
    const u16* __restrict__ xmb, const int* __restrict__ alistM, const int* __restrict__ cnts,
    const u16* __restrict__ w1pk, const float* __restrict__ fc1b,
    const u16* __restrict__ w2pk, const float* __restrict__ fc2b,
    u16* __restrict__ ycM){
  int e = blockIdx.y, tile = blockIdx.x, tid = threadIdx.x;
  int cnt = cnts[8+e]; int base = tile*32;
  if (base >= cnt) return;
  int nn = min(32, cnt - base); int off = e*131072;
  __shared__ int toks[32];
  __shared__ u16 xs[32*72];
  __shared__ u16 hT[32*264];     // [tok][ch]
  if (tid < 32) toks[tid] = alistM[off + base + min(tid, nn-1)];
  __syncthreads();
  { int row = tid >> 3, c0 = (tid & 7)*8;
    short8 v = *(const short8*)(xmb + (size_t)(toks[row]>>1)*64 + c0);
    *(short8*)&xs[row*72 + c0] = v; }
  __syncthreads();
  int lane = tid & 63, w = tid >> 6;
  int n = lane & 15, q = lane >> 4;
  int mt = w & 1;
  short8 x0 = *(const short8*)&xs[(mt*16 + n)*72 + q*8];
  short8 x1 = *(const short8*)&xs[(mt*16 + n)*72 + 32 + q*8];
  const short8* b1 = (const short8*)(w1pk + (size_t)e*16384);
  short8 b1f[16];
#pragma unroll
  for (int i=0;i<8;i++){
    int nt = (w>>1)*8 + i;
    b1f[2*i]   = b1[(nt*2+0)*64 + lane];
    b1f[2*i+1] = b1[(nt*2+1)*64 + lane];
  }
#pragma unroll
  for (int i=0;i<8;i++){
    int nt = (w>>1)*8 + i;
    f32x4 acc = {0.f,0.f,0.f,0.f};
    acc = MFMA16(b1f[2*i],   x0, acc);
    acc = MFMA16(b1f[2*i+1], x1, acc);
    f32x4 bias = *(const f32x4*)(fc1b + e*256 + nt*16 + q*4);
    s16x4 o;
#pragma unroll
    for (int r=0;r<4;r++) o[r] = (short)f2bu(geluf(acc[r] + bias[r]));
    *(s16x4*)&hT[(mt*16 + n)*264 + nt*16 + q*4] = o;   // b64, [tok][ch]
  }
  __syncthreads();
  short8 a2[8];
#pragma unroll
  for (int kc=0;kc<8;kc++) a2[kc] = *(const short8*)&hT[(mt*16 + n)*264 + kc*32 + q*8];
  const short8* b2 = (const short8*)(w2pk + (size_t)e*16384);
  bool valid = (mt*16 + n) < nn;
  int slot = toks[mt*16 + n];
#pragma unroll
  for (int i=0;i<2;i++){
    int nt = (w>>1)*2 + i;
    f32x4 acc = {0.f,0.f,0.f,0.f};
#pragma unroll
    for (int kc=0;kc<8;kc++) acc = MFMA16(b2[(nt*8+kc)*64 + lane], a2[kc], acc);
    f32x4 bias = *(const f32x4*)(fc2b + e*64 + nt*16 + q*4);
    if (valid){
      s16x4 o;
#pragma unroll
      for (int r=0;r<4;r++) o[r] = (short)f2bu(acc[r] + bias[r]);
      *(s16x4*)(ycM + (size_t)slot*64 + nt*16 + q*4) = o;   // 8B store
    }
  }
}

// ---------------- text MoE (MFMA): 16-token tiles ----------------
__global__ __launch_bounds__(256) void k_text_moe(
    const u16* __restrict__ xtb, const int* __restrict__ alistT, const int* __restrict__ cnts,
    const u16* __restrict__ w1pk, const float* __restrict__ fc1b,
    const u16* __restrict__ w2pk, const float* __restrict__ fc2b,
    float* __restrict__ ycT){
  int e = blockIdx.y, tile = blockIdx.x, tid = threadIdx.x;
  int cnt = cnts[e]; int base = tile*16;
  if (base >= cnt) return;
  int nn = min(16, cnt - base); int off = e*4928;
  __shared__ int toks[16];
  __shared__ u16 xs[16*280];
  __shared__ u16 hT[16*1048];
  if (tid < 16) toks[tid] = alistT[off + base + min(tid, nn-1)];
  __syncthreads();
  { int row = tid >> 4, c0 = (tid & 15)*16;
    const short8* sp = (const short8*)(xtb + (size_t)(toks[row]>>1)*256 + c0);
    short8 v0 = sp[0], v1 = sp[1];
    *(short8*)&xs[row*280 + c0] = v0;
    *(short8*)&xs[row*280 + c0 + 8] = v1; }
  __syncthreads();
  int lane = tid & 63, w = tid >> 6;
  int n = lane & 15, q = lane >> 4;
  short8 a_[8];
#pragma unroll
  for (int kc=0;kc<8;kc++) a_[kc] = *(const short8*)&xs[n*280 + kc*32 + q*8];
  const short8* b1 = (const short8*)(w1pk + (size_t)e*262144);
#pragma unroll 1
  for (int i=0;i<16;i++){
    int nt = w*16 + i;
    f32x4 acc = {0.f,0.f,0.f,0.f};
#pragma unroll
    for (int kc=0;kc<8;kc++) acc = MFMA16(a_[kc], b1[(nt*8+kc)*64 + lane], acc);
    float bias = fc1b[e*1024 + nt*16 + n];
#pragma unroll
    for (int r=0;r<4;r++)
      hT[(q*4 + r)*1048 + nt*16 + n] = f2bu(geluf(acc[r] + bias));
  }
  __syncthreads();
  const short8* b2 = (const short8*)(w2pk + (size_t)e*262144);
  f32x4 acc[4];
#pragma unroll
  for (int i=0;i<4;i++) acc[i] = (f32x4){0.f,0.f,0.f,0.f};
#pragma unroll 1
  for (int kc=0;kc<32;kc++){
    short8 a = *(const short8*)&hT[n*1048 + kc*32 + q*8];
#pragma unroll
    for (int i=0;i<4;i++){
      int nt = w*4 + i;
      acc[i] = MFMA16(a, b2[(nt*32+kc)*64 + lane], acc[i]);
    }
  }
#pragma unroll
  for (int i=0;i<4;i++){
    int nt = w*4 + i;
    float bias = fc2b[e*256 + nt*16 + n];
#pragma unroll
    for (int r=0;r<4;r++){
      int row = q*4 + r;
      if (row < nn) ycT[(size_t)toks[row]*256 + nt*16 + n] = acc[i][r] + bias;
    }
  }
}

// combine 2 expert contributions (gate-weighted), gelu, proj 256->128 -> tfeat
__global__ __launch_bounds__(128) void k_text_combine(
    const float* __restrict__ ycT, const float2* __restrict__ ewT,
    const float* __restrict__ pw, const float* __restrict__ pb,
    float* __restrict__ tfeat){
  int t = blockIdx.x, tid = threadIdx.x;
  __shared__ float gy[256];
  float2 w = ewT[t];
  for (int c=tid; c<256; c+=128){
    float y = w.x*ycT[(size_t)(t*2)*256 + c] + w.y*ycT[(size_t)(t*2+1)*256 + c];
    gy[c] = geluf(y);
  }
  __syncthreads();
  float a = pb[tid];
  for (int k=0;k<256;k++) a += gy[k] * pw[k*128 + tid];
  tfeat[(size_t)t*128 + tid] = a;
}

// motion combine + gelu + proj 64->256 (MFMA) -> mf bf16, fused q-softmax.
__global__ __launch_bounds__(256) void k_mproj(
    const u16* __restrict__ ycM, const float2* __restrict__ ewM,
    const u16* __restrict__ wpk, const float* __restrict__ pb,
    u16* __restrict__ mf, u16* __restrict__ qs){
  int t0 = blockIdx.x*32, tid = threadIdx.x;
  __shared__ u16 xs[32*72];
  { int row = tid >> 3, c0 = (tid & 7)*8;
    int tok = t0 + row;
    float2 wgt = ewM[tok];
    short8 v0 = *(const short8*)(ycM + (size_t)(tok*2)*64 + c0);
    short8 v1 = *(const short8*)(ycM + (size_t)(tok*2+1)*64 + c0);
    short8 o;
#pragma unroll
    for (int j=0;j<8;j++)
      o[j] = (short)f2bu(geluf(wgt.x*bu2f((u16)v0[j]) + wgt.y*bu2f((u16)v1[j])));
    *(short8*)&xs[row*72 + c0] = o; }
  __syncthreads();
  int lane = tid & 63, w = tid >> 6;
  int n = lane & 15, q = lane >> 4;
  int mt = w & 1;
  short8 a0 = *(const short8*)&xs[(mt*16 + n)*72 + q*8];
  short8 a1 = *(const short8*)&xs[(mt*16 + n)*72 + 32 + q*8];
  const short8* bp = (const short8*)wpk;
  float vals[4][4];   // [nt-12][r], only waves 2,3
#pragma unroll
  for (int i=0;i<8;i++){
    int nt = (w>>1)*8 + i;
    f32x4 acc = {0.f,0.f,0.f,0.f};
    acc = MFMA16(a0, bp[(nt*2+0)*64 + lane], acc);
    acc = MFMA16(a1, bp[(nt*2+1)*64 + lane], acc);
    float bias = pb[nt*16 + n];
#pragma unroll
    for (int r=0;r<4;r++){
      float v = acc[r] + bias;
      if (w >= 2 && i >= 4) vals[i-4][r] = v;
      int tok = t0 + mt*16 + q*4 + r;
      mf[(size_t)tok*256 + nt*16 + n] = f2bu(v);
    }
  }
  if (w >= 2){
#pragma unroll
    for (int r=0;r<4;r++){
      int tok = t0 + mt*16 + q*4 + r;
      float m = fmaxf(fmaxf(vals[0][r], vals[1][r]), fmaxf(vals[2][r], vals[3][r]));
#pragma unroll
      for (int o=8;o>0;o>>=1) m = fmaxf(m, __shfl_xor(m, o, 64));
      float e0 = expf(vals[0][r]-m), e1 = expf(vals[1][r]-m);
      float e2 = expf(vals[2][r]-m), e3 = expf(vals[3][r]-m);
      float s = (e0+e1) + (e2+e3);
#pragma unroll
      for (int o=8;o>0;o>>=1) s += __shfl_xor(s, o, 64);
      float inv = __builtin_amdgcn_rcpf(s);
      u16* qp = qs + (size_t)tok*64 + n;
      qp[0]  = f2bu(e0*inv);
      qp[16] = f2bu(e1*inv);
      qp[32] = f2bu(e2*inv);
      qp[48] = f2bu(e3*inv);
    }
  }
}

// ---------------- eo = silu(emb) @ (2048x1024) + b : split-K tiled f32 ----------------
__global__ __launch_bounds__(256) void k_eo1(const float* __restrict__ emb, const float* __restrict__ ew,
                      float* __restrict__ ep){
  int ct = blockIdx.x & 15;
  int ks = blockIdx.x >> 4;
  int tid = threadIdx.x;
  int k0 = ks*128, c0 = ct*64;
  __shared__ float aS[128*68];
  __shared__ float bS[128*64];
#pragma unroll
  for (int i=0;i<8;i++){
    int idx4 = tid + i*256;
    int b = idx4 >> 5, kq = idx4 & 31;
    f32x4 v = *(const f32x4*)(emb + (size_t)b*2048 + k0 + kq*4);
    aS[(kq*4+0)*68 + b] = siluf(v[0]);
    aS[(kq*4+1)*68 + b] = siluf(v[1]);
    aS[(kq*4+2)*68 + b] = siluf(v[2]);
    aS[(kq*4+3)*68 + b] = siluf(v[3]);
  }
#pragma unroll
  for (int i=0;i<8;i++){
    int idx4 = tid + i*256;
    int kk = idx4 >> 4, cq = idx4 & 15;
    *(f32x4*)&bS[kk*64 + cq*4] = *(const f32x4*)(ew + (size_t)(k0+kk)*1024 + c0 + cq*4);
  }
  __syncthreads();
  int cg = tid & 15, bg = tid >> 4;
  f32x4 acc[4] = {{0.f,0.f,0.f,0.f},{0.f,0.f,0.f,0.f},{0.f,0.f,0.f,0.f},{0.f,0.f,0.f,0.f}};
#pragma unroll 4
  for (int kk=0;kk<128;kk++){
    f32x4 a = *(const f32x4*)&aS[kk*68 + bg*4];
    f32x4 bb = *(const f32x4*)&bS[kk*64 + cg*4];
#pragma unroll
    for (int i=0;i<4;i++){
      acc[i][0] += a[i]*bb[0];
      acc[i][1] += a[i]*bb[1];
      acc[i][2] += a[i]*bb[2];
      acc[i][3] += a[i]*bb[3];
    }
  }
#pragma unroll
  for (int i=0;i<4;i++){
    int b = bg*4 + i;
    *(f32x4*)&ep[((size_t)(ks*64 + b))*1024 + c0 + cg*4] = acc[i];
  }
}

__global__ __launch_bounds__(256) void k_eo2(const float* __restrict__ ep, const float* __restrict__ ebias,
                      float* __restrict__ eo){
  int idx = blockIdx.x*256 + threadIdx.x;
  int c = idx & 1023;
  float s = ebias[c];
#pragma unroll
  for (int ks=0;ks<16;ks++) s += ep[(size_t)ks*65536 + idx];
  eo[idx] = s;
}

// ---------------- attention + y_t fused: per (b,h) block ----------------
// Phase 1: single-pass LDS softmax + MFMA -> attnT in LDS (stride 76 u16).
// Phase 2: y_t = qs @ attnT (M=256 over 8 waves, K=64, N=64) -> yt global.
#define AT_STRIDE 364
#define AS_STRIDE 76    // attnS row stride: 38 words = 6 mod 32, bank-spread
__global__ __launch_bounds__(512) void k_attn(const float* __restrict__ tfeat, const u16* __restrict__ mf,
                       const float* __restrict__ src_mask, const int* __restrict__ cond,
                       const u16* __restrict__ qs, u16* __restrict__ yt){
  int b = blockIdx.x >> 3; int h = blockIdx.x & 7;
  int tid = threadIdx.x; int c = tid & 63; int part = tid >> 6;
  __shared__ u16 ebT[64*AT_STRIDE];
  __shared__ u16 vbT[64*AT_STRIDE];
  __shared__ float colmax[64], colsum[64], red[512];
  float tc = ((cond[b] % 10) > 0) ? 1.f : 0.f;
  float negt = (1.f - tc) * (-1e6f);

  float mx = -1e30f;
  for (int k = 0; k < 11; k++){
    int n0 = part*44 + k*4;
    s16x4 kb4, vb4;
#pragma unroll
    for (int jj = 0; jj < 4; jj++){
      int n = n0 + jj;
      float kv, vv;
      if (n < 77){
        const float* trow = tfeat + (b*77+n)*128;
        kv = trow[c] + negt;
        vv = trow[64 + c] * tc;
      } else if (n < 333){
        int t = n - 77; float smv = src_mask[b*256 + t];
        const u16* mrow = mf + ((size_t)(b*256+t)*8+h)*256;
        kv = bu2f(mrow[64 + c]) + (1.f - smv)*(-1e6f);
        vv = bu2f(mrow[128 + c]) * smv;
      } else { kv = -1e30f; vv = 0.f; }
      kb4[jj] = (short)f2bu(kv);
      vb4[jj] = (short)f2bu(vv);
      mx = fmaxf(mx, kv);
    }
    *(s16x4*)&ebT[c*AT_STRIDE + n0] = kb4;
    *(s16x4*)&vbT[c*AT_STRIDE + n0] = vb4;
  }
  red[tid] = mx; __syncthreads();
  if (part == 0){
    float m = red[c];
#pragma unroll
    for (int p=1;p<8;p++) m = fmaxf(m, red[p*64 + c]);
    colmax[c] = m;
  }
  __syncthreads();
  { int rowc = tid >> 3, j = tid & 7;
    float cm = colmax[rowc];
    float s = 0.f;
    for (int k = 0; k < 11; k++){
      int n0 = (j*11 + k)*4;
      s16x4 v4 = *(const s16x4*)&ebT[rowc*AT_STRIDE + n0];
      float e0 = expf(bu2f((u16)v4[0]) - cm);
      float e1 = expf(bu2f((u16)v4[1]) - cm);
      float e2 = expf(bu2f((u16)v4[2]) - cm);
      float e3 = expf(bu2f((u16)v4[3]) - cm);
      s += (e0+e1) + (e2+e3);
      s16x4 o;
      o[0]=(short)f2bu(e0); o[1]=(short)f2bu(e1); o[2]=(short)f2bu(e2); o[3]=(short)f2bu(e3);
      *(s16x4*)&ebT[rowc*AT_STRIDE + n0] = o;
    }
    red[tid] = s;
  }
  __syncthreads();
  if (tid < 64){
    float t2 = 0.f;
#pragma unroll
    for (int p=0;p<8;p++) t2 += red[tid*8 + p];
    colsum[tid] = t2;
  }
  __syncthreads();
  int lane = tid & 63, w = tid >> 6;
  int n16 = lane & 15, q = lane >> 4;
  int mt = w >> 1;
  int ntb = (w & 1) * 2;
  f32x4 acc0 = {0.f,0.f,0.f,0.f}, acc1 = {0.f,0.f,0.f,0.f};
  const u16* ea = &ebT[(mt*16 + n16)*AT_STRIDE + q*8];
  const u16* v0p = &vbT[(ntb*16 + n16)*AT_STRIDE + q*8];
  const u16* v1p = &vbT[((ntb+1)*16 + n16)*AT_STRIDE + q*8];
#pragma unroll
  for (int kc = 0; kc < 11; kc++){
    short8 a  = ld8(ea  + kc*32);
    short8 b0 = ld8(v0p + kc*32);
    short8 b1 = ld8(v1p + kc*32);
    acc0 = MFMA16(a, b0, acc0);
    acc1 = MFMA16(a, b1, acc1);
  }
  float inv[4];
#pragma unroll
  for (int r=0;r<4;r++) inv[r] = __builtin_amdgcn_rcpf(colsum[mt*16 + q*4 + r]);
  // write attnT[l][d] into LDS (alias ebT; all ebT reads done after barrier)
  __syncthreads();
  u16* attnS = ebT;
  {
    int d0 = mt*16 + q*4;
    int l0 = ntb*16 + n16, l1 = (ntb+1)*16 + n16;
    s16x4 o0, o1;
#pragma unroll
    for (int r=0;r<4;r++){ o0[r] = (short)f2bu(acc0[r]*inv[r]); o1[r] = (short)f2bu(acc1[r]*inv[r]); }
    *(s16x4*)&attnS[l0*AS_STRIDE + d0] = o0;
    *(s16x4*)&attnS[l1*AS_STRIDE + d0] = o1;
  }
  __syncthreads();
  // phase 2: y_t = qs @ attnT. 8 waves x 32 rows.
  const u16* qsb = qs + ((size_t)(b*256)*8 + h)*64;   // row stride 512 u16
  f32x4 ya[2][4];
#pragma unroll
  for (int m2=0;m2<2;m2++)
#pragma unroll
    for (int nt=0;nt<4;nt++) ya[m2][nt] = (f32x4){0.f,0.f,0.f,0.f};
#pragma unroll
  for (int kc=0;kc<2;kc++){
    short8 a0 = *(const short8*)(qsb + (size_t)(w*32 + n16)*512 + kc*32 + q*8);
    short8 a1 = *(const short8*)(qsb + (size_t)(w*32 + 16 + n16)*512 + kc*32 + q*8);
    short8 b_[4];
#pragma unroll
    for (int nt=0;nt<4;nt++) b_[nt] = ld8(&attnS[(nt*16 + n16)*AS_STRIDE + kc*32 + q*8]);
#pragma unroll
    for (int nt=0;nt<4;nt++){
      ya[0][nt] = MFMA16(a0, b_[nt], ya[0][nt]);
      ya[1][nt] = MFMA16(a1, b_[nt], ya[1][nt]);
    }
  }
#pragma unroll
  for (int m2=0;m2<2;m2++)
#pragma unroll
    for (int nt=0;nt<4;nt++){
      int l = nt*16 + n16;
#pragma unroll
      for (int r=0;r<4;r++){
        int t = w*32 + m2*16 + q*4 + r;
        yt[((size_t)(b*256+t)*8 + h)*64 + l] = f2bu(ya[m2][nt][r]);
      }
    }
}

// ---------------- out = x + silu(mod(LN(body+yt))) @ W + b  (j2 fused in) ----------------
__global__ __launch_bounds__(256) void k_out(const u16* __restrict__ wpk,
                      const float* __restrict__ bias, const float* __restrict__ x,
                      const u16* __restrict__ mf, const u16* __restrict__ yt,
                      const float* __restrict__ bwv, const float* __restrict__ eo,
                      const float* __restrict__ sb_ng, const float* __restrict__ sb_nb,
                      float* __restrict__ out){
  int r0 = blockIdx.x*32, tid = threadIdx.x;
  int b = r0 >> 8;                       // 8 blocks per batch row-group
  __shared__ u16 xs[32*536];
  __shared__ u16 mfl[32*520];            // [row][h*64+l] bf16, stride 520
  // stage mf (body-feat slice, dd<64 of each head) for 32 rows
#pragma unroll
  for (int i=0;i<8;i++){
    int idx = tid + i*256;               // 2048 short8 chunks
    int rw = idx >> 6, rem = idx & 63;
    int hh = rem >> 3, d0 = (rem & 7)*8;
    *(short8*)&mfl[rw*520 + hh*64 + d0] =
      *(const short8*)(mf + (((size_t)(r0+rw)*8 + hh)*256) + d0);
  }
  __syncthreads();
  // j2 math: thread = (row, h), 64 l-channels
  {
    int row = tid >> 3, hh = tid & 7;
    float bw8[8];
#pragma unroll
    for (int lh=0;lh<8;lh++) bw8[lh] = bwv[hh*8 + lh];
    const u16* ytrow = yt + (((size_t)(r0+row)*8 + hh)*64);
    float out64[64];
    float s1 = 0.f, s2 = 0.f;
#pragma unroll
    for (int lc=0;lc<8;lc++){
      short8 yv = *(const short8*)(ytrow + lc*8);
      float o[8];
#pragma unroll
      for (int j=0;j<8;j++) o[j] = bu2f((u16)yv[j]);
#pragma unroll
      for (int lh=0;lh<8;lh++){
        short8 m = *(const short8*)&mfl[row*520 + lh*64 + lc*8];
#pragma unroll
        for (int j=0;j<8;j++) o[j] = fmaf(bw8[lh], bu2f((u16)m[j]), o[j]);
      }
#pragma unroll
      for (int j=0;j<8;j++){ out64[lc*8+j] = o[j]; s1 += o[j]; s2 += o[j]*o[j]; }
    }
    // LN over the row's 512 channels: reduce across the 8 h-lanes
    s1 += __shfl_xor(s1, 1, 64); s2 += __shfl_xor(s2, 1, 64);
    s1 += __shfl_xor(s1, 2, 64); s2 += __shfl_xor(s2, 2, 64);
    s1 += __shfl_xor(s1, 4, 64); s2 += __shfl_xor(s2, 4, 64);
    float mean = s1 * (1.f/512.f);
    float var  = s2 * (1.f/512.f) - mean*mean;
    float rr = rsqrtf(var + 1e-5f);
#pragma unroll
    for (int lc=0;lc<8;lc++){
      short8 o8;
#pragma unroll
      for (int j=0;j<8;j++){
        int cch = hh*64 + lc*8 + j;
        float hn = (out64[lc*8+j]-mean)*rr*sb_ng[cch] + sb_nb[cch];
        float hm = hn*(1.f + eo[b*1024 + cch]) + eo[b*1024 + 512 + cch];
        o8[j] = (short)f2bu(siluf(hm));
      }
      *(short8*)&xs[row*536 + hh*64 + lc*8] = o8;
    }
  }
  __syncthreads();
  int lane = tid & 63, w = tid >> 6;
  int n = lane & 15, q = lane >> 4;
  int mt = w & 1;
  short8 a_[16];
#pragma unroll
  for (int kc=0;kc<16;kc++) a_[kc] = *(const short8*)&xs[(mt*16 + n)*536 + kc*32 + q*8];
  const short8* bp = (const short8*)wpk;
#pragma unroll 1
  for (int i=0;i<16;i++){
    int nt = (w>>1)*16 + i;
    f32x4 acc = {0.f,0.f,0.f,0.f};
#pragma unroll
    for (int kc=0;kc<16;kc++) acc = MFMA16(a_[kc], bp[(nt*16+kc)*64 + lane], acc);
    int col = nt*16 + n;
    float bv = bias[col];
#pragma unroll
    for (int r=0;r<4;r++){
      size_t rowg = (size_t)(r0 + mt*16 + q*4 + r);
      out[rowg*512 + col] = acc[r] + bv + x[rowg*512 + col];
    }
  }
}

extern "C" void kernel_launch(void* const* d_in, const int* in_sizes, int n_in,
                              void* d_out, int out_size, void* d_ws, size_t ws_size,
                              hipStream_t stream) {
  (void)in_sizes; (void)n_in; (void)out_size; (void)ws_size;
  const float* x        = (const float*)d_in[0];
  const float* xf       = (const float*)d_in[1];
  const float* emb      = (const float*)d_in[2];
  const float* src_mask = (const float*)d_in[3];
  const float* norm_g   = (const float*)d_in[4];
  const float* norm_b   = (const float*)d_in[5];
  const float* tnorm_g  = (const float*)d_in[6];
  const float* tnorm_b  = (const float*)d_in[7];
  const float* m_pos    = (const float*)d_in[8];
  const float* m_gate   = (const float*)d_in[9];
  const float* m_fc1w   = (const float*)d_in[10];
  const float* m_fc1b   = (const float*)d_in[11];
  const float* m_fc2w   = (const float*)d_in[12];
  const float* m_fc2b   = (const float*)d_in[13];
  const float* m_projw  = (const float*)d_in[14];
  const float* m_projb  = (const float*)d_in[15];
  const float* t_pos    = (const float*)d_in[16];
  const float* t_gate   = (const float*)d_in[17];
  const float* t_fc1w   = (const float*)d_in[18];
  const float* t_fc1b   = (const float*)d_in[19];
  const float* t_fc2w   = (const float*)d_in[20];
  const float* t_fc2b   = (const float*)d_in[21];
  const float* t_projw  = (const float*)d_in[22];
  const float* t_projb  = (const float*)d_in[23];
  const float* body_w   = (const float*)d_in[24];
  const float* sb_embw  = (const float*)d_in[25];
  const float* sb_embb  = (const float*)d_in[26];
  const float* sb_ng    = (const float*)d_in[27];
  const float* sb_nb    = (const float*)d_in[28];
  const float* sb_outw  = (const float*)d_in[29];
  const float* sb_outb  = (const float*)d_in[30];
  const int*   cond     = (const int*)d_in[31];

  // ---- workspace, manual lifetime aliasing ----
  char* base = (char*)d_ws;
  size_t o = 0;
  auto alloc = [&](size_t bytes)->char*{ char* r = base + o; o += (bytes + 255) & ~(size_t)255; return r; };
  u16*  mf      = (u16*)alloc(67108864);    // motion_feat bf16, live to end
  char* R       = alloc(33554432);          // aliased region
  float* ep     = (float*)(R);              // eo partials, dead before xtb use
  u16*  xtb     = (u16*)(R);                // dead after k_text_moe
  float* ycT    = (float*)(R + 4194304);    // dead after k_text_combine
  u16*  ycM     = (u16*)(R);                // dead after k_mproj
  u16*  yt      = (u16*)(R + 8388608);      // written by fused k_attn
  u16*  xmb     = (u16*)alloc(16777216);    // dead after k_motion_moe
  u16*  qs      = xmb;                      // reuses xmb space (written in k_mproj)
  u16*  t1pk    = (u16*)alloc(4194304);
  u16*  t2pk    = (u16*)alloc(4194304);
  u16*  m1pk    = (u16*)alloc(262144);
  u16*  m2pk    = (u16*)alloc(262144);
  u16*  mppk    = (u16*)alloc(32768);
  u16*  wopk    = (u16*)alloc(524288);
  int2* eidxT   = (int2*)alloc(39424);
  float2* ewT   = (float2*)alloc(39424);
  int2* eidxM   = (int2*)alloc(1048576);
  float2* ewM   = (float2*)alloc(1048576);
  int*  alistT  = (int*)alloc(157696);      // [8][4928] strided
  int*  alistM  = (int*)alloc(4194304);     // [8][131072] strided
  int*  cnts    = (int*)alloc(256);
  float* tfeat  = (float*)alloc(2523136);
  float* eo     = (float*)alloc(262144);
  float* bwv    = (float*)alloc(256);

  // setup (merged): init + one repack + eo GEMM
  k_init<<<1, 64, 0, stream>>>(cnts, body_w, bwv);
  k_repack_all<<<18496, 256, 0, stream>>>(t_fc1w, t1pk, t_fc2w, t2pk, m_fc1w, m1pk,
                                          m_fc2w, m2pk, m_projw, mppk, sb_outw, wopk);
  k_eo1<<<256, 256, 0, stream>>>(emb, sb_embw, ep);
  k_eo2<<<256, 256, 0, stream>>>(ep, sb_embb, eo);

  // pre + direct routing (no count/scan)
  k_text_pre<<<4928, 256, 0, stream>>>(xf, tnorm_g, tnorm_b, t_pos, t_gate, xtb, eidxT, ewT);
  k_motion_pre<<<32768, 256, 0, stream>>>(x, norm_g, norm_b, m_pos, m_gate, xmb, eidxM, ewM);
  k_filld<<<32, 256, 0, stream>>>(eidxT, 4928, 4928, cnts, alistT);
  k_filld<<<256, 256, 0, stream>>>(eidxM, 131072, 131072, cnts + 8, alistM);

  // text MoE (MFMA) then combine
  k_text_moe<<<dim3(308, 8), 256, 0, stream>>>(xtb, alistT, cnts, t1pk, t_fc1b, t2pk, t_fc2b, ycT);
  k_text_combine<<<4928, 128, 0, stream>>>(ycT, ewT, t_projw, t_projb, tfeat);

  // motion MoE v2 then combine+proj (fused q-softmax)
  k_motion_moe<<<dim3(4096, 8), 256, 0, stream>>>(xmb, alistM, cnts, m1pk, m_fc1b, m2pk, m_fc2b, ycM);
  k_mproj<<<4096, 256, 0, stream>>>(ycM, ewM, mppk, m_projb, mf, qs);

  // fused attention + y_t, then fused j2 + out
  k_attn<<<512, 512, 0, stream>>>(tfeat, mf, src_mask, cond, qs, yt);
  k_out<<<512, 256, 0, stream>>>(wopk, sb_outb, x, mf, yt, bwv, eo, sb_ng, sb_nb, (float*)d_out);
}